// Round 8
// baseline (1977.495 us; speedup 1.0000x reference)
//
#include <hip/hip_runtime.h>
#include <hip/hip_bf16.h>
#include <math.h>

#define PAD 2

typedef __attribute__((ext_vector_type(8))) short s8v;    // 8 bf16 = 4 VGPRs
typedef __attribute__((ext_vector_type(4))) float f4v;    // 4 fp32 acc

__device__ __forceinline__ f4v mfma16(s8v a, s8v b, f4v c){
    return __builtin_amdgcn_mfma_f32_16x16x32_bf16(a, b, c, 0, 0, 0);
}

__device__ __forceinline__ unsigned short f2bf(float f){
    unsigned u = __float_as_uint(f);
    unsigned r = u + 0x7FFFu + ((u >> 16) & 1u);
    return (unsigned short)(r >> 16);
}

// ---- ordered-uint encoding for float atomicMax ----
__device__ __forceinline__ unsigned f2o(float f){
    unsigned b = __float_as_uint(f);
    return (b & 0x80000000u) ? ~b : (b | 0x80000000u);
}
__device__ __forceinline__ float o2f(unsigned u){
    return __uint_as_float((u & 0x80000000u) ? (u & 0x7fffffffu) : ~u);
}

__device__ __forceinline__ float bperm(int adr, float v){
    return __uint_as_float((unsigned)__builtin_amdgcn_ds_bpermute(adr, (int)__float_as_uint(v)));
}

// ============================================================
// corr v2 (verified r5): wave = 64-px row-band; tap shifts via
// ds_bpermute; c-split LDS-combined + atomicAdd.
// ============================================================
__global__ __launch_bounds__(256)
void corr_v2(const float* __restrict__ key, const float* __restrict__ frame,
             float* __restrict__ corr,
             int C, int CW, int H, int W, int logHW, int logW){
    const int tid = threadIdx.x, lane = tid & 63, wv = tid >> 6;
    const int HW = 1 << logHW;
    const int p0 = blockIdx.x * 64;
    const int b  = p0 >> logHW;
    const int remL = (p0 & (HW - 1)) + lane;
    const int y = remL >> logW, x = remL & (W - 1);

    float m[25];
    #pragma unroll
    for (int t = 0; t < 25; t++){
        const int dy = t / 5 - 2, dx = t % 5 - 2;
        m[t] = (((unsigned)(y + dy) < (unsigned)H) &&
                ((unsigned)(x + dx) < (unsigned)W)) ? 1.f : 0.f;
    }
    int adr[4];
    const int dxs[4] = {-2, -1, 1, 2};
    #pragma unroll
    for (int i = 0; i < 4; i++) adr[i] = ((lane + dxs[i]) & 63) << 2;

    int roff[5];
    #pragma unroll
    for (int r = 0; r < 5; r++){
        const int dy = r - 2;
        roff[r] = ((unsigned)(y + dy) < (unsigned)H) ? dy * W : 0;
    }

    const int c0 = (blockIdx.y * 4 + wv) * CW;
    const float* kp = key   + (((size_t)b * C + c0) << logHW) + remL;
    const float* fp = frame + (((size_t)b * C + c0) << logHW) + remL;

    float acc[25];
    #pragma unroll
    for (int t = 0; t < 25; t++) acc[t] = 0.f;

    for (int ci = 0; ci < CW; ci++){
        const float k = kp[0];
        float f[5];
        #pragma unroll
        for (int r = 0; r < 5; r++) f[r] = fp[roff[r]];
        #pragma unroll
        for (int r = 0; r < 5; r++){
            float v[5];
            v[0] = bperm(adr[0], f[r]);
            v[1] = bperm(adr[1], f[r]);
            v[2] = f[r];
            v[3] = bperm(adr[2], f[r]);
            v[4] = bperm(adr[3], f[r]);
            #pragma unroll
            for (int j = 0; j < 5; j++)
                acc[r * 5 + j] += k * (v[j] * m[r * 5 + j]);
        }
        kp += HW; fp += HW;
    }

    __shared__ float sacc[4][25][64];
    #pragma unroll
    for (int t = 0; t < 25; t++) sacc[wv][t][lane] = acc[t];
    __syncthreads();
    #pragma unroll
    for (int tg = 0; tg < 7; tg++){
        const int t = wv + tg * 4;
        if (t < 25){
            const float s = sacc[0][t][lane] + sacc[1][t][lane] +
                            sacc[2][t][lane] + sacc[3][t][lane];
            atomicAdd(corr + (((size_t)b * 25 + t) << logHW) + remL, s);
        }
    }
}

// ============================================================
// global max over the summed corr buffer (runs after corr_v2).
// ============================================================
__global__ void max_kernel(const float* __restrict__ corr, unsigned* __restrict__ gmax){
    float v = corr[(size_t)blockIdx.x * 256 + threadIdx.x];
    #pragma unroll
    for (int o = 32; o > 0; o >>= 1) v = fmaxf(v, __shfl_down(v, o));
    if ((threadIdx.x & 63) == 0) atomicMax(gmax, f2o(v));
}

// ============================================================
// att: softmax over the 25 offsets, in-place on corr buffer.
// ============================================================
__global__ void att_kernel(float* __restrict__ corr, const unsigned* __restrict__ gmax,
                           int logHW){
    const int p = blockIdx.x * 256 + threadIdx.x;
    const int b = p >> logHW;
    const int rem = p & ((1 << logHW) - 1);
    float* cp = corr + (((size_t)b * 25) << logHW) + rem;
    const float scale = 20.f / o2f(*gmax);

    float z[25]; float m = -INFINITY;
    #pragma unroll
    for (int k = 0; k < 25; k++){
        z[k] = cp[k << logHW] * scale;
        m = fmaxf(m, z[k]);
    }
    float s = 0.f;
    #pragma unroll
    for (int k = 0; k < 25; k++){ z[k] = expf(z[k] - m); s += z[k]; }
    const float inv = 1.f / s;
    #pragma unroll
    for (int k = 0; k < 25; k++) cp[k << logHW] = z[k] * inv;
}

// ============================================================
// warp v2 (verified r5)
// ============================================================
__global__ __launch_bounds__(256)
void warp_v2(const float* __restrict__ frame, const float* __restrict__ att,
             float* __restrict__ newf,
             int C, int CW, int H, int W, int logHW, int logW){
    const int tid = threadIdx.x, lane = tid & 63, wv = tid >> 6;
    const int HW = 1 << logHW;
    const int p0 = blockIdx.x * 64;
    const int b  = p0 >> logHW;
    const int remL = (p0 & (HW - 1)) + lane;
    const int y = remL >> logW, x = remL & (W - 1);

    int adr[4];
    const int dxs[4] = {-2, -1, 1, 2};
    #pragma unroll
    for (int i = 0; i < 4; i++) adr[i] = ((lane + dxs[i]) & 63) << 2;

    int roff[5];
    #pragma unroll
    for (int r = 0; r < 5; r++){
        const int dy = r - 2;
        roff[r] = ((unsigned)(y + dy) < (unsigned)H) ? dy * W : 0;
    }

    const float* ap = att + (((size_t)b * 25) << logHW) + remL;
    float a[25];
    #pragma unroll
    for (int t = 0; t < 25; t++){
        const int dy = t / 5 - 2, dx = t % 5 - 2;
        const float mk = (((unsigned)(y + dy) < (unsigned)H) &&
                          ((unsigned)(x + dx) < (unsigned)W)) ? 1.f : 0.f;
        a[t] = ap[(size_t)t << logHW] * mk;
    }

    const int c0 = (blockIdx.y * 4 + wv) * CW;
    const float* fp = frame + (((size_t)b * C + c0) << logHW) + remL;
    float*       op = newf  + (((size_t)b * C + c0) << logHW) + remL;

    for (int ci = 0; ci < CW; ci++){
        float f[5];
        #pragma unroll
        for (int r = 0; r < 5; r++) f[r] = fp[roff[r]];
        float acc = 0.f;
        #pragma unroll
        for (int r = 0; r < 5; r++){
            float v[5];
            v[0] = bperm(adr[0], f[r]);
            v[1] = bperm(adr[1], f[r]);
            v[2] = f[r];
            v[3] = bperm(adr[2], f[r]);
            v[4] = bperm(adr[3], f[r]);
            #pragma unroll
            for (int j = 0; j < 5; j++)
                acc += a[r * 5 + j] * v[j];
        }
        op[0] = acc;
        fp += HW; op += HW;
    }
}

// ============================================================
// gate v2 (verified r5)
// ============================================================
__global__ __launch_bounds__(256)
void gate_v2(const float* __restrict__ key, const float* __restrict__ newf,
             const float* __restrict__ Wg, float* __restrict__ gz,
             int C, int CW, int H, int W, int logHW, int logW){
    const int tid = threadIdx.x, lane = tid & 63, wv = tid >> 6;
    const int HW = 1 << logHW;
    const int p0 = blockIdx.x * 64;
    const int b  = p0 >> logHW;
    const int remL = (p0 & (HW - 1)) + lane;
    const int y = remL >> logW, x = remL & (W - 1);

    float m[9];
    #pragma unroll
    for (int t = 0; t < 9; t++){
        const int dy = t / 3 - 1, dx = t % 3 - 1;
        m[t] = (((unsigned)(y + dy) < (unsigned)H) &&
                ((unsigned)(x + dx) < (unsigned)W)) ? 1.f : 0.f;
    }
    const int adrL = ((lane - 1) & 63) << 2;
    const int adrR = ((lane + 1) & 63) << 2;

    int roff[3];
    #pragma unroll
    for (int r = 0; r < 3; r++){
        const int dy = r - 1;
        roff[r] = ((unsigned)(y + dy) < (unsigned)H) ? dy * W : 0;
    }

    const int c0 = (blockIdx.y * 4 + wv) * CW;   // u in [0, 2C); chunk never straddles C
    const float* base = (c0 < C)
        ? key  + (((size_t)b * C + c0)       << logHW)
        : newf + (((size_t)b * C + (c0 - C)) << logHW);
    const float* ip = base + remL;

    float z0 = 0.f, z1 = 0.f;
    for (int ci = 0; ci < CW; ci++){
        const int u = c0 + ci;
        const float* w0 = Wg + (size_t)u * 9;
        const float* w1 = Wg + ((size_t)2 * C + u) * 9;
        float f[3];
        #pragma unroll
        for (int r = 0; r < 3; r++) f[r] = ip[roff[r]];
        #pragma unroll
        for (int r = 0; r < 3; r++){
            float v[3];
            v[0] = bperm(adrL, f[r]);
            v[1] = f[r];
            v[2] = bperm(adrR, f[r]);
            #pragma unroll
            for (int j = 0; j < 3; j++){
                const float val = v[j] * m[r * 3 + j];
                z0 += val * w0[r * 3 + j];
                z1 += val * w1[r * 3 + j];
            }
        }
        ip += HW;
    }

    __shared__ float sz[2][4][64];
    sz[0][wv][lane] = z0; sz[1][wv][lane] = z1;
    __syncthreads();
    if (wv < 2){
        const float s = sz[wv][0][lane] + sz[wv][1][lane] +
                        sz[wv][2][lane] + sz[wv][3][lane];
        atomicAdd(gz + ((size_t)b * 2 + wv) * HW + remL, s);
    }
}

// ============================================================
// prep_gin: NCHW fp32 (key,new) * sigmoid(gz+bg) -> NHWC bf16 gin
// ============================================================
__global__ void prep_gin(const float* __restrict__ key, const float* __restrict__ newf,
                         const float* __restrict__ g, const float* __restrict__ bg,
                         unsigned short* __restrict__ gin,
                         int C, int HW){
    __shared__ unsigned short tile[64][65];
    int tid = threadIdx.x;
    int pt0 = blockIdx.x * 64;
    int u0  = blockIdx.y * 64;
    int b   = pt0 / HW;
    int rem0 = pt0 - b * HW;
    const float* gb = g + (size_t)(b * 2) * HW;

    #pragma unroll
    for (int it = 0; it < 16; it++){
        int idx = it * 256 + tid;
        int ur = idx >> 6, pc = idx & 63;
        int u = u0 + ur; int rem = rem0 + pc;
        const float* src; int sel;
        if (u < C){ src = key  + ((size_t)b * C + u) * HW;       sel = 0; }
        else      { src = newf + ((size_t)b * C + (u - C)) * HW; sel = 1; }
        float zz = gb[(size_t)sel * HW + rem] + bg[sel];
        float gv = 1.f / (1.f + expf(-zz));
        float v = src[rem] * gv;
        tile[ur][pc] = f2bf(v);
    }
    __syncthreads();
    unsigned short* go = gin + (size_t)pt0 * (2 * C) + u0;
    #pragma unroll
    for (int it = 0; it < 16; it++){
        int idx = it * 256 + tid;
        int pr = idx >> 6, uc = idx & 63;
        go[(size_t)pr * (2 * C) + uc] = tile[uc][pr];
    }
}

// ============================================================
// prep_w: W[co][ci][t] fp32 -> Wt[co][t*Cin+ci] bf16
// ============================================================
__global__ void prep_w(const float* __restrict__ W, unsigned short* __restrict__ Wt,
                       int Cin){
    int ci = blockIdx.y * 256 + threadIdx.x;
    int bx = blockIdx.x;
    int co = bx / 9, t = bx - co * 9;
    Wt[(size_t)bx * Cin + ci] = f2bf(W[((size_t)co * Cin + ci) * 9 + t]);
}

// ============================================================
// conv_mfma v7: BM=32, 128-thread blocks (2 waves, 1x2 wave grid),
// pair-step reg-staged pipeline (from v6), XCD-aware 1D grid.
// v6 had 2 barrier-lockstepped blocks/CU -> SIMDs idle at every
// drain. Now 1024 blocks = 4 independent barrier groups/CU (same
// 8 waves/CU), barrier scope = 2 waves. XCD decode: wgid&7 picks
// the weight panel (Ny=8: panel=xcd; Ny=2: panel=xcd>>2, x-range
// split by xcd&3) -> each XCD's B panel is L2-resident.
// LDS: 4 bufs: sA 4x2KB + sB 4x(BN/16)KB = 40KB(BN=128)/24KB(64).
// ============================================================
template<int BN, int EPI>
__global__ __launch_bounds__(128, 2)
void conv_mfma(const unsigned short* __restrict__ gin,
               const unsigned short* __restrict__ Wt,
               const float* __restrict__ bias,
               unsigned short* __restrict__ obf, int ostride,
               float* __restrict__ of32,
               const void* __restrict__ zp,
               int Cin, int Cout, int H, int W, int logHW, int logW,
               int Mt, int Ny)
{
    constexpr int BM = 32;
    constexpr int BNh = BN / 2;
    constexpr int NJ = BN / 32;      // 16-col fragments per wave
    constexpr int NR = BN / 32;      // 32-row staging rounds per K-block
    __shared__ __align__(16) unsigned short sA[4][BM * 32];
    __shared__ __align__(16) unsigned short sB[4][BN * 32];

    const int tid = threadIdx.x;
    const int lane = tid & 63;
    const int wn = tid >> 6;               // 2 waves: col-split
    const int ln = lane & 15, q = lane >> 4;

    // XCD-aware decode: 1D grid of Mt*Ny blocks.
    const int wgid = blockIdx.x;
    int xt, yt;
    if (Ny == 8){ yt = wgid & 7; xt = wgid >> 3; }
    else        { const int xcd = wgid & 7; yt = xcd >> 2;
                  xt = (xcd & 3) * (Mt >> 2) + (wgid >> 3); }

    const int p0 = xt * BM;
    const int b  = p0 >> logHW;
    const int rem0 = p0 - (b << logHW);

    // staging: row = tid>>2 (0..31); swizzled 16B chunk within 64B row
    const int rowA0 = tid >> 2;
    const int gc8 = ((tid & 3) ^ ((tid >> 3) & 3)) * 8;    // element offset
    const int remA0 = rem0 + rowA0;
    const int yA0 = remA0 >> logW, xA0 = remA0 & (W - 1);
    const size_t pbase = ((size_t)b << logHW);

    const int nt0 = yt * BN;
    const size_t Ktot = (size_t)9 * Cin;
    const unsigned short* wB0 = Wt + (size_t)(nt0 + rowA0) * Ktot + gc8;

    f4v acc[2][NJ];
    #pragma unroll
    for (int i = 0; i < 2; i++)
        #pragma unroll
        for (int j = 0; j < NJ; j++){ f4v z = {0.f, 0.f, 0.f, 0.f}; acc[i][j] = z; }

    const int cblocks = Cin >> 5;
    const int total = 9 * cblocks;       // 144/216/288/432 — always even
    const int npairs = total >> 1;       // 72/108/144/216 — always even

    // staging-cursor state (for the NEXT K-block to issue)
    int scb = 0;                                   // k-chunk within tap
    int st  = 0;                                   // tap index
    bool sv = (yA0 > 0) && (xA0 > 0);              // tap 0: dy=-1,dx=-1
    const unsigned short* sa  = gin + (pbase + remA0 + (-W - 1)) * Cin + gc8;
    const unsigned short* swb = wB0;               // +32 per issued K-block

    struct Regs { f4v a; f4v bb[NR]; };
    Regs R0, R1, R2, R3;

    auto issue1 = [&](Regs& r){
        r.a = *(const f4v*)(sv ? (const void*)(sa + scb * 32) : zp);
        #pragma unroll
        for (int rd = 0; rd < NR; rd++)
            r.bb[rd] = *(const f4v*)(swb + (size_t)rd * 32 * Ktot);
        swb += 32;
        if (++scb == cblocks){
            scb = 0; ++st;
            const int dy = st / 3 - 1, dx = st - (st / 3) * 3 - 1;
            sv = ((unsigned)(yA0 + dy) < (unsigned)H) && ((unsigned)(xA0 + dx) < (unsigned)W);
            sa = gin + (pbase + remA0 + dy * W + dx) * Cin + gc8;
        }
    };
    auto commit1 = [&](const Regs& r, int buf){
        *(f4v*)((char*)sA[buf] + (size_t)tid * 16) = r.a;
        char* dB = (char*)sB[buf];
        #pragma unroll
        for (int rd = 0; rd < NR; rd++)
            *(f4v*)(dB + rd * 2048 + (size_t)tid * 16) = r.bb[rd];
    };

    const int rchunk = (q ^ ((ln >> 1) & 3)) * 8;   // swizzled read offset
    auto compute1 = [&](int buf){
        const unsigned short* A = sA[buf];
        const unsigned short* B = sB[buf];
        s8v af[2];
        #pragma unroll
        for (int i = 0; i < 2; i++)
            af[i] = *(const s8v*)(A + (i * 16 + ln) * 32 + rchunk);
        __builtin_amdgcn_s_setprio(1);
        #pragma unroll
        for (int j = 0; j < NJ; j++){
            s8v bfr = *(const s8v*)(B + (wn * BNh + j * 16 + ln) * 32 + rchunk);
            #pragma unroll
            for (int i = 0; i < 2; i++)
                acc[i][j] = mfma16(af[i], bfr, acc[i][j]);
        }
        __builtin_amdgcn_s_setprio(0);
    };

    // loads per pair per thread = 2*(1+NR): BN=128 -> 10, BN=64 -> 6
    #define WAIT_CUR()  do{ if constexpr (BN == 128) asm volatile("s_waitcnt vmcnt(10)" ::: "memory"); \
                            else                     asm volatile("s_waitcnt vmcnt(6)" ::: "memory"); }while(0)
    #define WAIT_ALL()  asm volatile("s_waitcnt vmcnt(0)" ::: "memory")

    // prologue: pairs 0 and 1 in flight
    issue1(R0); issue1(R1); issue1(R2); issue1(R3);

    for (int t = 0; t < npairs; t += 2){
        // ---- pair t: regs R0,R1 -> bufs 0,1 ----
        if (t + 1 < npairs) WAIT_CUR(); else WAIT_ALL();
        __builtin_amdgcn_sched_barrier(0);
        commit1(R0, 0); commit1(R1, 1);
        if (t + 2 < npairs){ issue1(R0); issue1(R1); }   // pair t+2
        asm volatile("s_waitcnt lgkmcnt(0)" ::: "memory");
        __builtin_amdgcn_sched_barrier(0);
        __builtin_amdgcn_s_barrier();
        compute1(0); compute1(1);

        // ---- pair t+1: regs R2,R3 -> bufs 2,3 ----
        if (t + 2 < npairs) WAIT_CUR(); else WAIT_ALL();
        __builtin_amdgcn_sched_barrier(0);
        commit1(R2, 2); commit1(R3, 3);
        if (t + 3 < npairs){ issue1(R2); issue1(R3); }   // pair t+3
        asm volatile("s_waitcnt lgkmcnt(0)" ::: "memory");
        __builtin_amdgcn_sched_barrier(0);
        __builtin_amdgcn_s_barrier();
        compute1(2); compute1(3);
    }
    #undef WAIT_CUR
    #undef WAIT_ALL

    // epilogue: D rows m = i*16 + q*4 + r (pixels), cols n (cout)
    #pragma unroll
    for (int i = 0; i < 2; i++){
        const int m0 = i * 16 + q * 4;
        const int p = p0 + m0;
        #pragma unroll
        for (int j = 0; j < NJ; j++){
            const int n = nt0 + wn * BNh + j * 16 + ln;
            const float bv = bias[n];
            if (EPI == 0){
                #pragma unroll
                for (int r = 0; r < 4; r++){
                    float v = fmaxf(acc[i][j][r] + bv, 0.f);
                    obf[(size_t)(p + r) * ostride + n] = f2bf(v);
                }
            } else {
                f4v o;
                #pragma unroll
                for (int r = 0; r < 4; r++) o[r] = fmaxf(acc[i][j][r] + bv, 0.f);
                const int rem = rem0 + m0;
                *(f4v*)(of32 + (((size_t)b * Cout + n) << logHW) + rem) = o;
            }
        }
    }
}

// ============================================================
extern "C" void kernel_launch(void* const* d_in, const int* in_sizes, int n_in,
                              void* d_out, int out_size, void* d_ws, size_t ws_size,
                              hipStream_t stream){
    (void)in_sizes; (void)n_in; (void)out_size; (void)ws_size;

    const float* X[4][2];
    for (int s = 0; s < 4; s++)
        for (int l = 0; l < 2; l++)
            X[s][l] = (const float*)d_in[s * 2 + l];
    const float* Wg[2] = { (const float*)d_in[8],  (const float*)d_in[14] };
    const float* bg[2] = { (const float*)d_in[9],  (const float*)d_in[15] };
    const float* Wd[2] = { (const float*)d_in[10], (const float*)d_in[16] };
    const float* bd[2] = { (const float*)d_in[11], (const float*)d_in[17] };
    const float* Wc[2] = { (const float*)d_in[12], (const float*)d_in[18] };
    const float* bc[2] = { (const float*)d_in[13], (const float*)d_in[19] };
    float* out = (float*)d_out;

    char* ws = (char*)d_ws;
    unsigned* gmax = (unsigned*)ws;
    const void* zp = (const void*)(ws + 1024);
    float* corrbuf = (float*)(ws + 4096);
    float* newbuf  = (float*)(ws + 4096 + 1638400);
    unsigned short* wtbuf = (unsigned short*)newbuf;   // alias, disjoint lifetime
    float* gbuf    = (float*)(ws + 4096 + 1638400 + 16777216);
    unsigned short* ginbuf = (unsigned short*)(ws + 4096 + 1638400 + 16777216 + 131072);
    unsigned short* totbuf = (unsigned short*)(ws + 4096 + 1638400 + 16777216 + 131072 + 16777216);

    hipMemsetAsync(ws, 0, 4096, stream);

    const int Cs[2] = {256, 512};
    const int Hs[2] = {64, 32};
    const int logWs[2] = {6, 5};
    const int logHWs[2] = {12, 10};
    const size_t outOff[2] = {0, (size_t)4 * 256 * 4096};

    for (int l = 0; l < 2; l++){
        const int C = Cs[l], H = Hs[l], W = Hs[l], HW = H * W;
        const int logW = logWs[l], logHW = logHWs[l];
        const float* key = X[3][l];
        const int pblk = 4 * HW / 256;
        const int Mt = 4 * HW / 32;            // BM=32 tiles: {2048/..}: l0=512? (see below)

        const int gx  = 4 * HW / 64;           // row-band tiles: {256, 64}
        const int S   = (l == 0) ? 2 : 8;      // c-split across grid.y -> 512 blocks
        const int CWc = C / (4 * S);           // channels per wave (corr/warp)
        const int CWg = (2 * C) / (4 * S);     // channels per wave (gate)

        const int Ny  = (l == 0) ? 2 : 8;      // weight panels (C/BN)

        for (int s = 0; s < 3; s++){
            const float* fr = X[s][l];
            unsigned* slot = gmax + (l * 3 + s);
            hipMemsetAsync(corrbuf, 0, (size_t)4 * 25 * HW * 4, stream);
            hipMemsetAsync(gbuf,    0, (size_t)4 * 2 * HW * 4, stream);
            corr_v2<<<dim3(gx, S), 256, 0, stream>>>(
                key, fr, corrbuf, C, CWc, H, W, logHW, logW);
            max_kernel<<<25 * 4 * HW / 256, 256, 0, stream>>>(corrbuf, slot);
            att_kernel<<<pblk, 256, 0, stream>>>(corrbuf, slot, logHW);
            warp_v2<<<dim3(gx, S), 256, 0, stream>>>(
                fr, corrbuf, newbuf, C, CWc, H, W, logHW, logW);
            gate_v2<<<dim3(gx, S), 256, 0, stream>>>(
                key, newbuf, Wg[l] + (size_t)s * 2 * (2 * C) * 9,
                gbuf, C, CWg, H, W, logHW, logW);
            prep_gin<<<dim3(4 * HW / 64, 2 * C / 64), 256, 0, stream>>>(
                key, newbuf, gbuf, bg[l] + (size_t)s * 2, ginbuf, C, HW);
            prep_w<<<dim3(C * 9, 2 * C / 256), 256, 0, stream>>>(
                Wd[l] + (size_t)s * C * 2 * C * 9, wtbuf, 2 * C);
            if (l == 0)
                conv_mfma<128, 0><<<dim3(Mt * Ny), 128, 0, stream>>>(
                    ginbuf, wtbuf, bd[l] + s * C, totbuf + s * C, 3 * C,
                    nullptr, zp, 2 * C, C, H, W, logHW, logW, Mt, Ny);
            else
                conv_mfma<64, 0><<<dim3(Mt * Ny), 128, 0, stream>>>(
                    ginbuf, wtbuf, bd[l] + s * C, totbuf + s * C, 3 * C,
                    nullptr, zp, 2 * C, C, H, W, logHW, logW, Mt, Ny);
        }
        prep_w<<<dim3(C * 9, 3 * C / 256), 256, 0, stream>>>(Wc[l], wtbuf, 3 * C);
        if (l == 0)
            conv_mfma<128, 1><<<dim3(Mt * Ny), 128, 0, stream>>>(
                totbuf, wtbuf, bc[l], nullptr, 0,
                out + outOff[l], zp, 3 * C, C, H, W, logHW, logW, Mt, Ny);
        else
            conv_mfma<64, 1><<<dim3(Mt * Ny), 128, 0, stream>>>(
                totbuf, wtbuf, bc[l], nullptr, 0,
                out + outOff[l], zp, 3 * C, C, H, W, logHW, logW, Mt, Ny);
    }
}

// Round 9
// 1919.793 us; speedup vs baseline: 1.0301x; 1.0301x over previous
//
#include <hip/hip_runtime.h>
#include <hip/hip_bf16.h>
#include <math.h>

#define PAD 2

typedef __attribute__((ext_vector_type(8))) short s8v;    // 8 bf16 = 4 VGPRs
typedef __attribute__((ext_vector_type(4))) float f4v;    // 4 fp32 acc

__device__ __forceinline__ f4v mfma16(s8v a, s8v b, f4v c){
    return __builtin_amdgcn_mfma_f32_16x16x32_bf16(a, b, c, 0, 0, 0);
}

__device__ __forceinline__ unsigned short f2bf(float f){
    unsigned u = __float_as_uint(f);
    unsigned r = u + 0x7FFFu + ((u >> 16) & 1u);
    return (unsigned short)(r >> 16);
}

// ---- ordered-uint encoding for float atomicMax ----
__device__ __forceinline__ unsigned f2o(float f){
    unsigned b = __float_as_uint(f);
    return (b & 0x80000000u) ? ~b : (b | 0x80000000u);
}
__device__ __forceinline__ float o2f(unsigned u){
    return __uint_as_float((u & 0x80000000u) ? (u & 0x7fffffffu) : ~u);
}

__device__ __forceinline__ float bperm(int adr, float v){
    return __uint_as_float((unsigned)__builtin_amdgcn_ds_bpermute(adr, (int)__float_as_uint(v)));
}

// ============================================================
// corr v2 (verified r5): wave = 64-px row-band; tap shifts via
// ds_bpermute; c-split LDS-combined + atomicAdd.
// ============================================================
__global__ __launch_bounds__(256)
void corr_v2(const float* __restrict__ key, const float* __restrict__ frame,
             float* __restrict__ corr,
             int C, int CW, int H, int W, int logHW, int logW){
    const int tid = threadIdx.x, lane = tid & 63, wv = tid >> 6;
    const int HW = 1 << logHW;
    const int p0 = blockIdx.x * 64;
    const int b  = p0 >> logHW;
    const int remL = (p0 & (HW - 1)) + lane;
    const int y = remL >> logW, x = remL & (W - 1);

    float m[25];
    #pragma unroll
    for (int t = 0; t < 25; t++){
        const int dy = t / 5 - 2, dx = t % 5 - 2;
        m[t] = (((unsigned)(y + dy) < (unsigned)H) &&
                ((unsigned)(x + dx) < (unsigned)W)) ? 1.f : 0.f;
    }
    int adr[4];
    const int dxs[4] = {-2, -1, 1, 2};
    #pragma unroll
    for (int i = 0; i < 4; i++) adr[i] = ((lane + dxs[i]) & 63) << 2;

    int roff[5];
    #pragma unroll
    for (int r = 0; r < 5; r++){
        const int dy = r - 2;
        roff[r] = ((unsigned)(y + dy) < (unsigned)H) ? dy * W : 0;
    }

    const int c0 = (blockIdx.y * 4 + wv) * CW;
    const float* kp = key   + (((size_t)b * C + c0) << logHW) + remL;
    const float* fp = frame + (((size_t)b * C + c0) << logHW) + remL;

    float acc[25];
    #pragma unroll
    for (int t = 0; t < 25; t++) acc[t] = 0.f;

    for (int ci = 0; ci < CW; ci++){
        const float k = kp[0];
        float f[5];
        #pragma unroll
        for (int r = 0; r < 5; r++) f[r] = fp[roff[r]];
        #pragma unroll
        for (int r = 0; r < 5; r++){
            float v[5];
            v[0] = bperm(adr[0], f[r]);
            v[1] = bperm(adr[1], f[r]);
            v[2] = f[r];
            v[3] = bperm(adr[2], f[r]);
            v[4] = bperm(adr[3], f[r]);
            #pragma unroll
            for (int j = 0; j < 5; j++)
                acc[r * 5 + j] += k * (v[j] * m[r * 5 + j]);
        }
        kp += HW; fp += HW;
    }

    __shared__ float sacc[4][25][64];
    #pragma unroll
    for (int t = 0; t < 25; t++) sacc[wv][t][lane] = acc[t];
    __syncthreads();
    #pragma unroll
    for (int tg = 0; tg < 7; tg++){
        const int t = wv + tg * 4;
        if (t < 25){
            const float s = sacc[0][t][lane] + sacc[1][t][lane] +
                            sacc[2][t][lane] + sacc[3][t][lane];
            atomicAdd(corr + (((size_t)b * 25 + t) << logHW) + remL, s);
        }
    }
}

// ============================================================
// global max over the summed corr buffer (runs after corr_v2).
// ============================================================
__global__ void max_kernel(const float* __restrict__ corr, unsigned* __restrict__ gmax){
    float v = corr[(size_t)blockIdx.x * 256 + threadIdx.x];
    #pragma unroll
    for (int o = 32; o > 0; o >>= 1) v = fmaxf(v, __shfl_down(v, o));
    if ((threadIdx.x & 63) == 0) atomicMax(gmax, f2o(v));
}

// ============================================================
// att: softmax over the 25 offsets, in-place on corr buffer.
// ============================================================
__global__ void att_kernel(float* __restrict__ corr, const unsigned* __restrict__ gmax,
                           int logHW){
    const int p = blockIdx.x * 256 + threadIdx.x;
    const int b = p >> logHW;
    const int rem = p & ((1 << logHW) - 1);
    float* cp = corr + (((size_t)b * 25) << logHW) + rem;
    const float scale = 20.f / o2f(*gmax);

    float z[25]; float m = -INFINITY;
    #pragma unroll
    for (int k = 0; k < 25; k++){
        z[k] = cp[k << logHW] * scale;
        m = fmaxf(m, z[k]);
    }
    float s = 0.f;
    #pragma unroll
    for (int k = 0; k < 25; k++){ z[k] = expf(z[k] - m); s += z[k]; }
    const float inv = 1.f / s;
    #pragma unroll
    for (int k = 0; k < 25; k++) cp[k << logHW] = z[k] * inv;
}

// ============================================================
// warp v2 (verified r5)
// ============================================================
__global__ __launch_bounds__(256)
void warp_v2(const float* __restrict__ frame, const float* __restrict__ att,
             float* __restrict__ newf,
             int C, int CW, int H, int W, int logHW, int logW){
    const int tid = threadIdx.x, lane = tid & 63, wv = tid >> 6;
    const int HW = 1 << logHW;
    const int p0 = blockIdx.x * 64;
    const int b  = p0 >> logHW;
    const int remL = (p0 & (HW - 1)) + lane;
    const int y = remL >> logW, x = remL & (W - 1);

    int adr[4];
    const int dxs[4] = {-2, -1, 1, 2};
    #pragma unroll
    for (int i = 0; i < 4; i++) adr[i] = ((lane + dxs[i]) & 63) << 2;

    int roff[5];
    #pragma unroll
    for (int r = 0; r < 5; r++){
        const int dy = r - 2;
        roff[r] = ((unsigned)(y + dy) < (unsigned)H) ? dy * W : 0;
    }

    const float* ap = att + (((size_t)b * 25) << logHW) + remL;
    float a[25];
    #pragma unroll
    for (int t = 0; t < 25; t++){
        const int dy = t / 5 - 2, dx = t % 5 - 2;
        const float mk = (((unsigned)(y + dy) < (unsigned)H) &&
                          ((unsigned)(x + dx) < (unsigned)W)) ? 1.f : 0.f;
        a[t] = ap[(size_t)t << logHW] * mk;
    }

    const int c0 = (blockIdx.y * 4 + wv) * CW;
    const float* fp = frame + (((size_t)b * C + c0) << logHW) + remL;
    float*       op = newf  + (((size_t)b * C + c0) << logHW) + remL;

    for (int ci = 0; ci < CW; ci++){
        float f[5];
        #pragma unroll
        for (int r = 0; r < 5; r++) f[r] = fp[roff[r]];
        float acc = 0.f;
        #pragma unroll
        for (int r = 0; r < 5; r++){
            float v[5];
            v[0] = bperm(adr[0], f[r]);
            v[1] = bperm(adr[1], f[r]);
            v[2] = f[r];
            v[3] = bperm(adr[2], f[r]);
            v[4] = bperm(adr[3], f[r]);
            #pragma unroll
            for (int j = 0; j < 5; j++)
                acc += a[r * 5 + j] * v[j];
        }
        op[0] = acc;
        fp += HW; op += HW;
    }
}

// ============================================================
// gate v2 (verified r5)
// ============================================================
__global__ __launch_bounds__(256)
void gate_v2(const float* __restrict__ key, const float* __restrict__ newf,
             const float* __restrict__ Wg, float* __restrict__ gz,
             int C, int CW, int H, int W, int logHW, int logW){
    const int tid = threadIdx.x, lane = tid & 63, wv = tid >> 6;
    const int HW = 1 << logHW;
    const int p0 = blockIdx.x * 64;
    const int b  = p0 >> logHW;
    const int remL = (p0 & (HW - 1)) + lane;
    const int y = remL >> logW, x = remL & (W - 1);

    float m[9];
    #pragma unroll
    for (int t = 0; t < 9; t++){
        const int dy = t / 3 - 1, dx = t % 3 - 1;
        m[t] = (((unsigned)(y + dy) < (unsigned)H) &&
                ((unsigned)(x + dx) < (unsigned)W)) ? 1.f : 0.f;
    }
    const int adrL = ((lane - 1) & 63) << 2;
    const int adrR = ((lane + 1) & 63) << 2;

    int roff[3];
    #pragma unroll
    for (int r = 0; r < 3; r++){
        const int dy = r - 1;
        roff[r] = ((unsigned)(y + dy) < (unsigned)H) ? dy * W : 0;
    }

    const int c0 = (blockIdx.y * 4 + wv) * CW;   // u in [0, 2C); chunk never straddles C
    const float* base = (c0 < C)
        ? key  + (((size_t)b * C + c0)       << logHW)
        : newf + (((size_t)b * C + (c0 - C)) << logHW);
    const float* ip = base + remL;

    float z0 = 0.f, z1 = 0.f;
    for (int ci = 0; ci < CW; ci++){
        const int u = c0 + ci;
        const float* w0 = Wg + (size_t)u * 9;
        const float* w1 = Wg + ((size_t)2 * C + u) * 9;
        float f[3];
        #pragma unroll
        for (int r = 0; r < 3; r++) f[r] = ip[roff[r]];
        #pragma unroll
        for (int r = 0; r < 3; r++){
            float v[3];
            v[0] = bperm(adrL, f[r]);
            v[1] = f[r];
            v[2] = bperm(adrR, f[r]);
            #pragma unroll
            for (int j = 0; j < 3; j++){
                const float val = v[j] * m[r * 3 + j];
                z0 += val * w0[r * 3 + j];
                z1 += val * w1[r * 3 + j];
            }
        }
        ip += HW;
    }

    __shared__ float sz[2][4][64];
    sz[0][wv][lane] = z0; sz[1][wv][lane] = z1;
    __syncthreads();
    if (wv < 2){
        const float s = sz[wv][0][lane] + sz[wv][1][lane] +
                        sz[wv][2][lane] + sz[wv][3][lane];
        atomicAdd(gz + ((size_t)b * 2 + wv) * HW + remL, s);
    }
}

// ============================================================
// prep_gin: NCHW fp32 (key,new) * sigmoid(gz+bg) -> NHWC bf16 gin
// ============================================================
__global__ void prep_gin(const float* __restrict__ key, const float* __restrict__ newf,
                         const float* __restrict__ g, const float* __restrict__ bg,
                         unsigned short* __restrict__ gin,
                         int C, int HW){
    __shared__ unsigned short tile[64][65];
    int tid = threadIdx.x;
    int pt0 = blockIdx.x * 64;
    int u0  = blockIdx.y * 64;
    int b   = pt0 / HW;
    int rem0 = pt0 - b * HW;
    const float* gb = g + (size_t)(b * 2) * HW;

    #pragma unroll
    for (int it = 0; it < 16; it++){
        int idx = it * 256 + tid;
        int ur = idx >> 6, pc = idx & 63;
        int u = u0 + ur; int rem = rem0 + pc;
        const float* src; int sel;
        if (u < C){ src = key  + ((size_t)b * C + u) * HW;       sel = 0; }
        else      { src = newf + ((size_t)b * C + (u - C)) * HW; sel = 1; }
        float zz = gb[(size_t)sel * HW + rem] + bg[sel];
        float gv = 1.f / (1.f + expf(-zz));
        float v = src[rem] * gv;
        tile[ur][pc] = f2bf(v);
    }
    __syncthreads();
    unsigned short* go = gin + (size_t)pt0 * (2 * C) + u0;
    #pragma unroll
    for (int it = 0; it < 16; it++){
        int idx = it * 256 + tid;
        int pr = idx >> 6, uc = idx & 63;
        go[(size_t)pr * (2 * C) + uc] = tile[uc][pr];
    }
}

// ============================================================
// prep_w: W[co][ci][t] fp32 -> Wt[co][t*Cin+ci] bf16
// ============================================================
__global__ void prep_w(const float* __restrict__ W, unsigned short* __restrict__ Wt,
                       int Cin){
    int ci = blockIdx.y * 256 + threadIdx.x;
    int bx = blockIdx.x;
    int co = bx / 9, t = bx - co * 9;
    Wt[(size_t)bx * Cin + ci] = f2bf(W[((size_t)co * Cin + ci) * 9 + t]);
}

// ============================================================
// conv_mfma v8: BM=32, 128-thread blocks, NATURAL 2D grid.
// r8's custom XCD decode destroyed A-tile sharing (FETCH 76->430MB):
// with natural dim3(Mt,Ny) and Mt%8==0, the Ny blocks sharing one
// A-tile all land on the SAME XCD (wgid = xt + Mt*yt, Mt*yt%8==0)
// -> gin re-reads are 8-way L2-shared, FETCH ~= weights x 8 XCDs.
// Keeps BM=32's TLP gain attempt: 1024 blocks = 4 independent
// 2-wave barrier groups/CU (vs v6's 2 lockstepped 4-wave groups).
// Pair-step reg-staged pipeline unchanged from v6/v7.
// LDS: 4 bufs x (2KB A + BN/16 KB B) = 40KB(BN=128)/24KB(BN=64).
// ============================================================
template<int BN, int EPI>
__global__ __launch_bounds__(128, 2)
void conv_mfma(const unsigned short* __restrict__ gin,
               const unsigned short* __restrict__ Wt,
               const float* __restrict__ bias,
               unsigned short* __restrict__ obf, int ostride,
               float* __restrict__ of32,
               const void* __restrict__ zp,
               int Cin, int Cout, int H, int W, int logHW, int logW)
{
    constexpr int BM = 32;
    constexpr int BNh = BN / 2;
    constexpr int NJ = BN / 32;      // 16-col fragments per wave
    constexpr int NR = BN / 32;      // 32-row staging rounds per K-block
    __shared__ __align__(16) unsigned short sA[4][BM * 32];
    __shared__ __align__(16) unsigned short sB[4][BN * 32];

    const int tid = threadIdx.x;
    const int lane = tid & 63;
    const int wn = tid >> 6;               // 2 waves: col-split
    const int ln = lane & 15, q = lane >> 4;

    const int xt = blockIdx.x, yt = blockIdx.y;   // natural mapping (A-share co-XCD)

    const int p0 = xt * BM;
    const int b  = p0 >> logHW;
    const int rem0 = p0 - (b << logHW);

    // staging: row = tid>>2 (0..31); swizzled 16B chunk within 64B row
    const int rowA0 = tid >> 2;
    const int gc8 = ((tid & 3) ^ ((tid >> 3) & 3)) * 8;    // element offset
    const int remA0 = rem0 + rowA0;
    const int yA0 = remA0 >> logW, xA0 = remA0 & (W - 1);
    const size_t pbase = ((size_t)b << logHW);

    const int nt0 = yt * BN;
    const size_t Ktot = (size_t)9 * Cin;
    const unsigned short* wB0 = Wt + (size_t)(nt0 + rowA0) * Ktot + gc8;

    f4v acc[2][NJ];
    #pragma unroll
    for (int i = 0; i < 2; i++)
        #pragma unroll
        for (int j = 0; j < NJ; j++){ f4v z = {0.f, 0.f, 0.f, 0.f}; acc[i][j] = z; }

    const int cblocks = Cin >> 5;
    const int total = 9 * cblocks;       // 144/216/288/432 — always even
    const int npairs = total >> 1;       // 72/108/144/216 — always even

    // staging-cursor state (for the NEXT K-block to issue)
    int scb = 0;                                   // k-chunk within tap
    int st  = 0;                                   // tap index
    bool sv = (yA0 > 0) && (xA0 > 0);              // tap 0: dy=-1,dx=-1
    const unsigned short* sa  = gin + (pbase + remA0 + (-W - 1)) * Cin + gc8;
    const unsigned short* swb = wB0;               // +32 per issued K-block

    struct Regs { f4v a; f4v bb[NR]; };
    Regs R0, R1, R2, R3;

    auto issue1 = [&](Regs& r){
        r.a = *(const f4v*)(sv ? (const void*)(sa + scb * 32) : zp);
        #pragma unroll
        for (int rd = 0; rd < NR; rd++)
            r.bb[rd] = *(const f4v*)(swb + (size_t)rd * 32 * Ktot);
        swb += 32;
        if (++scb == cblocks){
            scb = 0; ++st;
            const int dy = st / 3 - 1, dx = st - (st / 3) * 3 - 1;
            sv = ((unsigned)(yA0 + dy) < (unsigned)H) && ((unsigned)(xA0 + dx) < (unsigned)W);
            sa = gin + (pbase + remA0 + dy * W + dx) * Cin + gc8;
        }
    };
    auto commit1 = [&](const Regs& r, int buf){
        *(f4v*)((char*)sA[buf] + (size_t)tid * 16) = r.a;
        char* dB = (char*)sB[buf];
        #pragma unroll
        for (int rd = 0; rd < NR; rd++)
            *(f4v*)(dB + rd * 2048 + (size_t)tid * 16) = r.bb[rd];
    };

    const int rchunk = (q ^ ((ln >> 1) & 3)) * 8;   // swizzled read offset
    auto compute1 = [&](int buf){
        const unsigned short* A = sA[buf];
        const unsigned short* B = sB[buf];
        s8v af[2];
        #pragma unroll
        for (int i = 0; i < 2; i++)
            af[i] = *(const s8v*)(A + (i * 16 + ln) * 32 + rchunk);
        __builtin_amdgcn_s_setprio(1);
        #pragma unroll
        for (int j = 0; j < NJ; j++){
            s8v bfr = *(const s8v*)(B + (wn * BNh + j * 16 + ln) * 32 + rchunk);
            #pragma unroll
            for (int i = 0; i < 2; i++)
                acc[i][j] = mfma16(af[i], bfr, acc[i][j]);
        }
        __builtin_amdgcn_s_setprio(0);
    };

    // loads per pair per thread = 2*(1+NR): BN=128 -> 10, BN=64 -> 6
    #define WAIT_CUR()  do{ if constexpr (BN == 128) asm volatile("s_waitcnt vmcnt(10)" ::: "memory"); \
                            else                     asm volatile("s_waitcnt vmcnt(6)" ::: "memory"); }while(0)
    #define WAIT_ALL()  asm volatile("s_waitcnt vmcnt(0)" ::: "memory")

    // prologue: pairs 0 and 1 in flight
    issue1(R0); issue1(R1); issue1(R2); issue1(R3);

    for (int t = 0; t < npairs; t += 2){
        // ---- pair t: regs R0,R1 -> bufs 0,1 ----
        if (t + 1 < npairs) WAIT_CUR(); else WAIT_ALL();
        __builtin_amdgcn_sched_barrier(0);
        commit1(R0, 0); commit1(R1, 1);
        if (t + 2 < npairs){ issue1(R0); issue1(R1); }   // pair t+2
        asm volatile("s_waitcnt lgkmcnt(0)" ::: "memory");
        __builtin_amdgcn_sched_barrier(0);
        __builtin_amdgcn_s_barrier();
        compute1(0); compute1(1);

        // ---- pair t+1: regs R2,R3 -> bufs 2,3 ----
        if (t + 2 < npairs) WAIT_CUR(); else WAIT_ALL();
        __builtin_amdgcn_sched_barrier(0);
        commit1(R2, 2); commit1(R3, 3);
        if (t + 3 < npairs){ issue1(R2); issue1(R3); }   // pair t+3
        asm volatile("s_waitcnt lgkmcnt(0)" ::: "memory");
        __builtin_amdgcn_sched_barrier(0);
        __builtin_amdgcn_s_barrier();
        compute1(2); compute1(3);
    }
    #undef WAIT_CUR
    #undef WAIT_ALL

    // epilogue: D rows m = i*16 + q*4 + r (pixels), cols n (cout)
    #pragma unroll
    for (int i = 0; i < 2; i++){
        const int m0 = i * 16 + q * 4;
        const int p = p0 + m0;
        #pragma unroll
        for (int j = 0; j < NJ; j++){
            const int n = nt0 + wn * BNh + j * 16 + ln;
            const float bv = bias[n];
            if (EPI == 0){
                #pragma unroll
                for (int r = 0; r < 4; r++){
                    float v = fmaxf(acc[i][j][r] + bv, 0.f);
                    obf[(size_t)(p + r) * ostride + n] = f2bf(v);
                }
            } else {
                f4v o;
                #pragma unroll
                for (int r = 0; r < 4; r++) o[r] = fmaxf(acc[i][j][r] + bv, 0.f);
                const int rem = rem0 + m0;
                *(f4v*)(of32 + (((size_t)b * Cout + n) << logHW) + rem) = o;
            }
        }
    }
}

// ============================================================
extern "C" void kernel_launch(void* const* d_in, const int* in_sizes, int n_in,
                              void* d_out, int out_size, void* d_ws, size_t ws_size,
                              hipStream_t stream){
    (void)in_sizes; (void)n_in; (void)out_size; (void)ws_size;

    const float* X[4][2];
    for (int s = 0; s < 4; s++)
        for (int l = 0; l < 2; l++)
            X[s][l] = (const float*)d_in[s * 2 + l];
    const float* Wg[2] = { (const float*)d_in[8],  (const float*)d_in[14] };
    const float* bg[2] = { (const float*)d_in[9],  (const float*)d_in[15] };
    const float* Wd[2] = { (const float*)d_in[10], (const float*)d_in[16] };
    const float* bd[2] = { (const float*)d_in[11], (const float*)d_in[17] };
    const float* Wc[2] = { (const float*)d_in[12], (const float*)d_in[18] };
    const float* bc[2] = { (const float*)d_in[13], (const float*)d_in[19] };
    float* out = (float*)d_out;

    char* ws = (char*)d_ws;
    unsigned* gmax = (unsigned*)ws;
    const void* zp = (const void*)(ws + 1024);
    float* corrbuf = (float*)(ws + 4096);
    float* newbuf  = (float*)(ws + 4096 + 1638400);
    unsigned short* wtbuf = (unsigned short*)newbuf;   // alias, disjoint lifetime
    float* gbuf    = (float*)(ws + 4096 + 1638400 + 16777216);
    unsigned short* ginbuf = (unsigned short*)(ws + 4096 + 1638400 + 16777216 + 131072);
    unsigned short* totbuf = (unsigned short*)(ws + 4096 + 1638400 + 16777216 + 131072 + 16777216);

    hipMemsetAsync(ws, 0, 4096, stream);

    const int Cs[2] = {256, 512};
    const int Hs[2] = {64, 32};
    const int logWs[2] = {6, 5};
    const int logHWs[2] = {12, 10};
    const size_t outOff[2] = {0, (size_t)4 * 256 * 4096};

    for (int l = 0; l < 2; l++){
        const int C = Cs[l], H = Hs[l], W = Hs[l], HW = H * W;
        const int logW = logWs[l], logHW = logHWs[l];
        const float* key = X[3][l];
        const int pblk = 4 * HW / 256;
        const int Mt = 4 * HW / 32;            // BM=32 tiles: l0=512, l1=128 (both %8==0)

        const int gx  = 4 * HW / 64;           // row-band tiles: {256, 64}
        const int S   = (l == 0) ? 2 : 8;      // c-split across grid.y -> 512 blocks
        const int CWc = C / (4 * S);           // channels per wave (corr/warp)
        const int CWg = (2 * C) / (4 * S);     // channels per wave (gate)

        const int Ny  = (l == 0) ? 2 : 8;      // weight panels (C/BN)

        for (int s = 0; s < 3; s++){
            const float* fr = X[s][l];
            unsigned* slot = gmax + (l * 3 + s);
            hipMemsetAsync(corrbuf, 0, (size_t)4 * 25 * HW * 4, stream);
            hipMemsetAsync(gbuf,    0, (size_t)4 * 2 * HW * 4, stream);
            corr_v2<<<dim3(gx, S), 256, 0, stream>>>(
                key, fr, corrbuf, C, CWc, H, W, logHW, logW);
            max_kernel<<<25 * 4 * HW / 256, 256, 0, stream>>>(corrbuf, slot);
            att_kernel<<<pblk, 256, 0, stream>>>(corrbuf, slot, logHW);
            warp_v2<<<dim3(gx, S), 256, 0, stream>>>(
                fr, corrbuf, newbuf, C, CWc, H, W, logHW, logW);
            gate_v2<<<dim3(gx, S), 256, 0, stream>>>(
                key, newbuf, Wg[l] + (size_t)s * 2 * (2 * C) * 9,
                gbuf, C, CWg, H, W, logHW, logW);
            prep_gin<<<dim3(4 * HW / 64, 2 * C / 64), 256, 0, stream>>>(
                key, newbuf, gbuf, bg[l] + (size_t)s * 2, ginbuf, C, HW);
            prep_w<<<dim3(C * 9, 2 * C / 256), 256, 0, stream>>>(
                Wd[l] + (size_t)s * C * 2 * C * 9, wtbuf, 2 * C);
            if (l == 0)
                conv_mfma<128, 0><<<dim3(Mt, Ny), 128, 0, stream>>>(
                    ginbuf, wtbuf, bd[l] + s * C, totbuf + s * C, 3 * C,
                    nullptr, zp, 2 * C, C, H, W, logHW, logW);
            else
                conv_mfma<64, 0><<<dim3(Mt, Ny), 128, 0, stream>>>(
                    ginbuf, wtbuf, bd[l] + s * C, totbuf + s * C, 3 * C,
                    nullptr, zp, 2 * C, C, H, W, logHW, logW);
        }
        prep_w<<<dim3(C * 9, 3 * C / 256), 256, 0, stream>>>(Wc[l], wtbuf, 3 * C);
        if (l == 0)
            conv_mfma<128, 1><<<dim3(Mt, Ny), 128, 0, stream>>>(
                totbuf, wtbuf, bc[l], nullptr, 0,
                out + outOff[l], zp, 3 * C, C, H, W, logHW, logW);
        else
            conv_mfma<64, 1><<<dim3(Mt, Ny), 128, 0, stream>>>(
                totbuf, wtbuf, bc[l], nullptr, 0,
                out + outOff[l], zp, 3 * C, C, H, W, logHW, logW);
    }
}

// Round 10
// 1770.819 us; speedup vs baseline: 1.1167x; 1.0841x over previous
//
#include <hip/hip_runtime.h>
#include <hip/hip_bf16.h>
#include <math.h>

#define PAD 2

typedef __attribute__((ext_vector_type(8))) short s8v;    // 8 bf16 = 4 VGPRs
typedef __attribute__((ext_vector_type(4))) float f4v;    // 4 fp32 acc

__device__ __forceinline__ f4v mfma16(s8v a, s8v b, f4v c){
    return __builtin_amdgcn_mfma_f32_16x16x32_bf16(a, b, c, 0, 0, 0);
}

__device__ __forceinline__ unsigned short f2bf(float f){
    unsigned u = __float_as_uint(f);
    unsigned r = u + 0x7FFFu + ((u >> 16) & 1u);
    return (unsigned short)(r >> 16);
}

// ---- ordered-uint encoding for float atomicMax ----
__device__ __forceinline__ unsigned f2o(float f){
    unsigned b = __float_as_uint(f);
    return (b & 0x80000000u) ? ~b : (b | 0x80000000u);
}
__device__ __forceinline__ float o2f(unsigned u){
    return __uint_as_float((u & 0x80000000u) ? (u & 0x7fffffffu) : ~u);
}

__device__ __forceinline__ float bperm(int adr, float v){
    return __uint_as_float((unsigned)__builtin_amdgcn_ds_bpermute(adr, (int)__float_as_uint(v)));
}

// ============================================================
// corr v2 (verified r5): wave = 64-px row-band; tap shifts via
// ds_bpermute; c-split LDS-combined + atomicAdd.
// ============================================================
__global__ __launch_bounds__(256)
void corr_v2(const float* __restrict__ key, const float* __restrict__ frame,
             float* __restrict__ corr,
             int C, int CW, int H, int W, int logHW, int logW){
    const int tid = threadIdx.x, lane = tid & 63, wv = tid >> 6;
    const int HW = 1 << logHW;
    const int p0 = blockIdx.x * 64;
    const int b  = p0 >> logHW;
    const int remL = (p0 & (HW - 1)) + lane;
    const int y = remL >> logW, x = remL & (W - 1);

    float m[25];
    #pragma unroll
    for (int t = 0; t < 25; t++){
        const int dy = t / 5 - 2, dx = t % 5 - 2;
        m[t] = (((unsigned)(y + dy) < (unsigned)H) &&
                ((unsigned)(x + dx) < (unsigned)W)) ? 1.f : 0.f;
    }
    int adr[4];
    const int dxs[4] = {-2, -1, 1, 2};
    #pragma unroll
    for (int i = 0; i < 4; i++) adr[i] = ((lane + dxs[i]) & 63) << 2;

    int roff[5];
    #pragma unroll
    for (int r = 0; r < 5; r++){
        const int dy = r - 2;
        roff[r] = ((unsigned)(y + dy) < (unsigned)H) ? dy * W : 0;
    }

    const int c0 = (blockIdx.y * 4 + wv) * CW;
    const float* kp = key   + (((size_t)b * C + c0) << logHW) + remL;
    const float* fp = frame + (((size_t)b * C + c0) << logHW) + remL;

    float acc[25];
    #pragma unroll
    for (int t = 0; t < 25; t++) acc[t] = 0.f;

    for (int ci = 0; ci < CW; ci++){
        const float k = kp[0];
        float f[5];
        #pragma unroll
        for (int r = 0; r < 5; r++) f[r] = fp[roff[r]];
        #pragma unroll
        for (int r = 0; r < 5; r++){
            float v[5];
            v[0] = bperm(adr[0], f[r]);
            v[1] = bperm(adr[1], f[r]);
            v[2] = f[r];
            v[3] = bperm(adr[2], f[r]);
            v[4] = bperm(adr[3], f[r]);
            #pragma unroll
            for (int j = 0; j < 5; j++)
                acc[r * 5 + j] += k * (v[j] * m[r * 5 + j]);
        }
        kp += HW; fp += HW;
    }

    __shared__ float sacc[4][25][64];
    #pragma unroll
    for (int t = 0; t < 25; t++) sacc[wv][t][lane] = acc[t];
    __syncthreads();
    #pragma unroll
    for (int tg = 0; tg < 7; tg++){
        const int t = wv + tg * 4;
        if (t < 25){
            const float s = sacc[0][t][lane] + sacc[1][t][lane] +
                            sacc[2][t][lane] + sacc[3][t][lane];
            atomicAdd(corr + (((size_t)b * 25 + t) << logHW) + remL, s);
        }
    }
}

// ============================================================
// global max over the summed corr buffer (runs after corr_v2).
// ============================================================
__global__ void max_kernel(const float* __restrict__ corr, unsigned* __restrict__ gmax){
    float v = corr[(size_t)blockIdx.x * 256 + threadIdx.x];
    #pragma unroll
    for (int o = 32; o > 0; o >>= 1) v = fmaxf(v, __shfl_down(v, o));
    if ((threadIdx.x & 63) == 0) atomicMax(gmax, f2o(v));
}

// ============================================================
// warp v3: softmax FUSED into warp (att_kernel removed). Each
// wave loads its pixel's 25 raw corr sums, computes scale*softmax
// in registers (identical math to the old att_kernel: corr==0 at
// invalid taps, matching the zero-padded reference; mask applied
// after normalization), then the verified r5 row-band/bpermute
// gather. Saves 6 dispatches + a 25xHW read+write round-trip.
// ============================================================
__global__ __launch_bounds__(256)
void warp_v3(const float* __restrict__ frame, const float* __restrict__ corr,
             const unsigned* __restrict__ gmax, float* __restrict__ newf,
             int C, int CW, int H, int W, int logHW, int logW){
    const int tid = threadIdx.x, lane = tid & 63, wv = tid >> 6;
    const int HW = 1 << logHW;
    const int p0 = blockIdx.x * 64;
    const int b  = p0 >> logHW;
    const int remL = (p0 & (HW - 1)) + lane;
    const int y = remL >> logW, x = remL & (W - 1);

    int adr[4];
    const int dxs[4] = {-2, -1, 1, 2};
    #pragma unroll
    for (int i = 0; i < 4; i++) adr[i] = ((lane + dxs[i]) & 63) << 2;

    int roff[5];
    #pragma unroll
    for (int r = 0; r < 5; r++){
        const int dy = r - 2;
        roff[r] = ((unsigned)(y + dy) < (unsigned)H) ? dy * W : 0;
    }

    // in-register softmax over the 25 offsets
    const float scale = 20.f / o2f(*gmax);
    const float* cp = corr + (((size_t)b * 25) << logHW) + remL;
    float a[25]; float mx = -INFINITY;
    #pragma unroll
    for (int t = 0; t < 25; t++){
        a[t] = cp[(size_t)t << logHW] * scale;
        mx = fmaxf(mx, a[t]);
    }
    float ssum = 0.f;
    #pragma unroll
    for (int t = 0; t < 25; t++){ a[t] = expf(a[t] - mx); ssum += a[t]; }
    const float inv = 1.f / ssum;
    #pragma unroll
    for (int t = 0; t < 25; t++){
        const int dy = t / 5 - 2, dx = t % 5 - 2;
        const float mk = (((unsigned)(y + dy) < (unsigned)H) &&
                          ((unsigned)(x + dx) < (unsigned)W)) ? 1.f : 0.f;
        a[t] *= inv * mk;
    }

    const int c0 = (blockIdx.y * 4 + wv) * CW;
    const float* fp = frame + (((size_t)b * C + c0) << logHW) + remL;
    float*       op = newf  + (((size_t)b * C + c0) << logHW) + remL;

    for (int ci = 0; ci < CW; ci++){
        float f[5];
        #pragma unroll
        for (int r = 0; r < 5; r++) f[r] = fp[roff[r]];
        float acc = 0.f;
        #pragma unroll
        for (int r = 0; r < 5; r++){
            float v[5];
            v[0] = bperm(adr[0], f[r]);
            v[1] = bperm(adr[1], f[r]);
            v[2] = f[r];
            v[3] = bperm(adr[2], f[r]);
            v[4] = bperm(adr[3], f[r]);
            #pragma unroll
            for (int j = 0; j < 5; j++)
                acc += a[r * 5 + j] * v[j];
        }
        op[0] = acc;
        fp += HW; op += HW;
    }
}

// ============================================================
// gate v2 (verified r5)
// ============================================================
__global__ __launch_bounds__(256)
void gate_v2(const float* __restrict__ key, const float* __restrict__ newf,
             const float* __restrict__ Wg, float* __restrict__ gz,
             int C, int CW, int H, int W, int logHW, int logW){
    const int tid = threadIdx.x, lane = tid & 63, wv = tid >> 6;
    const int HW = 1 << logHW;
    const int p0 = blockIdx.x * 64;
    const int b  = p0 >> logHW;
    const int remL = (p0 & (HW - 1)) + lane;
    const int y = remL >> logW, x = remL & (W - 1);

    float m[9];
    #pragma unroll
    for (int t = 0; t < 9; t++){
        const int dy = t / 3 - 1, dx = t % 3 - 1;
        m[t] = (((unsigned)(y + dy) < (unsigned)H) &&
                ((unsigned)(x + dx) < (unsigned)W)) ? 1.f : 0.f;
    }
    const int adrL = ((lane - 1) & 63) << 2;
    const int adrR = ((lane + 1) & 63) << 2;

    int roff[3];
    #pragma unroll
    for (int r = 0; r < 3; r++){
        const int dy = r - 1;
        roff[r] = ((unsigned)(y + dy) < (unsigned)H) ? dy * W : 0;
    }

    const int c0 = (blockIdx.y * 4 + wv) * CW;   // u in [0, 2C); chunk never straddles C
    const float* base = (c0 < C)
        ? key  + (((size_t)b * C + c0)       << logHW)
        : newf + (((size_t)b * C + (c0 - C)) << logHW);
    const float* ip = base + remL;

    float z0 = 0.f, z1 = 0.f;
    for (int ci = 0; ci < CW; ci++){
        const int u = c0 + ci;
        const float* w0 = Wg + (size_t)u * 9;
        const float* w1 = Wg + ((size_t)2 * C + u) * 9;
        float f[3];
        #pragma unroll
        for (int r = 0; r < 3; r++) f[r] = ip[roff[r]];
        #pragma unroll
        for (int r = 0; r < 3; r++){
            float v[3];
            v[0] = bperm(adrL, f[r]);
            v[1] = f[r];
            v[2] = bperm(adrR, f[r]);
            #pragma unroll
            for (int j = 0; j < 3; j++){
                const float val = v[j] * m[r * 3 + j];
                z0 += val * w0[r * 3 + j];
                z1 += val * w1[r * 3 + j];
            }
        }
        ip += HW;
    }

    __shared__ float sz[2][4][64];
    sz[0][wv][lane] = z0; sz[1][wv][lane] = z1;
    __syncthreads();
    if (wv < 2){
        const float s = sz[wv][0][lane] + sz[wv][1][lane] +
                        sz[wv][2][lane] + sz[wv][3][lane];
        atomicAdd(gz + ((size_t)b * 2 + wv) * HW + remL, s);
    }
}

// ============================================================
// prep_gin: NCHW fp32 (key,new) * sigmoid(gz+bg) -> NHWC bf16 gin
// ============================================================
__global__ void prep_gin(const float* __restrict__ key, const float* __restrict__ newf,
                         const float* __restrict__ g, const float* __restrict__ bg,
                         unsigned short* __restrict__ gin,
                         int C, int HW){
    __shared__ unsigned short tile[64][65];
    int tid = threadIdx.x;
    int pt0 = blockIdx.x * 64;
    int u0  = blockIdx.y * 64;
    int b   = pt0 / HW;
    int rem0 = pt0 - b * HW;
    const float* gb = g + (size_t)(b * 2) * HW;

    #pragma unroll
    for (int it = 0; it < 16; it++){
        int idx = it * 256 + tid;
        int ur = idx >> 6, pc = idx & 63;
        int u = u0 + ur; int rem = rem0 + pc;
        const float* src; int sel;
        if (u < C){ src = key  + ((size_t)b * C + u) * HW;       sel = 0; }
        else      { src = newf + ((size_t)b * C + (u - C)) * HW; sel = 1; }
        float zz = gb[(size_t)sel * HW + rem] + bg[sel];
        float gv = 1.f / (1.f + expf(-zz));
        float v = src[rem] * gv;
        tile[ur][pc] = f2bf(v);
    }
    __syncthreads();
    unsigned short* go = gin + (size_t)pt0 * (2 * C) + u0;
    #pragma unroll
    for (int it = 0; it < 16; it++){
        int idx = it * 256 + tid;
        int pr = idx >> 6, uc = idx & 63;
        go[(size_t)pr * (2 * C) + uc] = tile[uc][pr];
    }
}

// ============================================================
// prep_w: W[co][ci][t] fp32 -> Wt[co][t*Cin+ci] bf16
// ============================================================
__global__ void prep_w(const float* __restrict__ W, unsigned short* __restrict__ Wt,
                       int Cin){
    int ci = blockIdx.y * 256 + threadIdx.x;
    int bx = blockIdx.x;
    int co = bx / 9, t = bx - co * 9;
    Wt[(size_t)bx * Cin + ci] = f2bf(W[((size_t)co * Cin + ci) * 9 + t]);
}

// ============================================================
// conv_mfma v6 (REVERTED — verified 119us in r7): BM=64, 256-thread
// pair-step reg-staged pipeline, natural 2D grid (A-tile sharers
// co-XCD since Mt%8==0 -> FETCH ~76MB). r8/r9 experiments refuted:
// custom XCD decode destroyed A-locality (430MB fetch); BM=32
// 2-wave blocks lost (B-staging per MFMA doubled, 141us).
// 4 LDS buffers, 2 pairs of loads in flight (counted vmcnt),
// one lgkmcnt(0)+s_barrier per pair, setprio around MFMA.
// ============================================================
template<int BN, int EPI>
__global__ __launch_bounds__(256, 2)
void conv_mfma(const unsigned short* __restrict__ gin,
               const unsigned short* __restrict__ Wt,
               const float* __restrict__ bias,
               unsigned short* __restrict__ obf, int ostride,
               float* __restrict__ of32,
               const void* __restrict__ zp,
               int Cin, int Cout, int H, int W, int logHW, int logW)
{
    constexpr int BM = 64;
    constexpr int BNh = BN / 2;
    constexpr int NJ = BN / 32;
    __shared__ __align__(16) unsigned short sA[4][BM * 32];
    __shared__ __align__(16) unsigned short sB[4][BN * 32];

    const int tid = threadIdx.x;
    const int lane = tid & 63;
    const int wv = tid >> 6;
    const int wm = wv >> 1, wn = wv & 1;
    const int ln = lane & 15, q = lane >> 4;

    const int p0 = blockIdx.x * BM;
    const int b  = p0 >> logHW;
    const int rem0 = p0 - (b << logHW);

    // staging: row = tid>>2 (0..63); swizzled global chunk
    const int rowA0 = tid >> 2;
    const int gc8 = ((tid & 3) ^ ((tid >> 3) & 3)) * 8;    // element offset
    const int remA0 = rem0 + rowA0;
    const int yA0 = remA0 >> logW, xA0 = remA0 & (W - 1);
    const size_t pbase = ((size_t)b << logHW);

    const int nt0 = blockIdx.y * BN;
    const size_t Ktot = (size_t)9 * Cin;
    const unsigned short* wB0 = Wt + (size_t)(nt0 + rowA0) * Ktot + gc8;

    f4v acc[2][NJ];
    #pragma unroll
    for (int i = 0; i < 2; i++)
        #pragma unroll
        for (int j = 0; j < NJ; j++){ f4v z = {0.f, 0.f, 0.f, 0.f}; acc[i][j] = z; }

    const int cblocks = Cin >> 5;
    const int total = 9 * cblocks;       // 144/216/288/432 — always even
    const int npairs = total >> 1;       // 72/108/144/216 — always even

    // staging-cursor state (for the NEXT K-block to issue)
    int scb = 0;                                   // k-chunk within tap
    int st  = 0;                                   // tap index
    bool sv = (yA0 > 0) && (xA0 > 0);              // tap 0: dy=-1,dx=-1
    const unsigned short* sa  = gin + (pbase + remA0 + (-W - 1)) * Cin + gc8;
    const unsigned short* swb = wB0;               // +32 per issued K-block

    struct Regs { f4v a, b0, b1; };
    Regs R0, R1, R2, R3;

    auto issue1 = [&](Regs& r){
        r.a  = *(const f4v*)(sv ? (const void*)(sa + scb * 32) : zp);
        r.b0 = *(const f4v*)swb;
        if constexpr (BN == 128) r.b1 = *(const f4v*)(swb + (size_t)64 * Ktot);
        swb += 32;
        if (++scb == cblocks){
            scb = 0; ++st;
            const int dy = st / 3 - 1, dx = st - (st / 3) * 3 - 1;
            sv = ((unsigned)(yA0 + dy) < (unsigned)H) && ((unsigned)(xA0 + dx) < (unsigned)W);
            sa = gin + (pbase + remA0 + dy * W + dx) * Cin + gc8;
        }
    };
    auto commit1 = [&](const Regs& r, int buf){
        *(f4v*)((char*)sA[buf] + (size_t)tid * 16) = r.a;
        char* dB = (char*)sB[buf];
        *(f4v*)(dB + (size_t)tid * 16) = r.b0;
        if constexpr (BN == 128) *(f4v*)(dB + 4096 + (size_t)tid * 16) = r.b1;
    };

    const int rchunk = (q ^ ((ln >> 1) & 3)) * 8;   // swizzled read offset
    auto compute1 = [&](int buf){
        const unsigned short* A = sA[buf];
        const unsigned short* B = sB[buf];
        s8v af[2];
        #pragma unroll
        for (int i = 0; i < 2; i++)
            af[i] = *(const s8v*)(A + (wm * 32 + i * 16 + ln) * 32 + rchunk);
        __builtin_amdgcn_s_setprio(1);
        #pragma unroll
        for (int j = 0; j < NJ; j++){
            s8v bfr = *(const s8v*)(B + (wn * BNh + j * 16 + ln) * 32 + rchunk);
            #pragma unroll
            for (int i = 0; i < 2; i++)
                acc[i][j] = mfma16(af[i], bfr, acc[i][j]);
        }
        __builtin_amdgcn_s_setprio(0);
    };

    // vmcnt literal = loads per PAIR still in flight (BN==128 -> 6, else 4)
    #define WAIT_CUR()  do{ if constexpr (BN == 128) asm volatile("s_waitcnt vmcnt(6)" ::: "memory"); \
                            else                     asm volatile("s_waitcnt vmcnt(4)" ::: "memory"); }while(0)
    #define WAIT_ALL()  asm volatile("s_waitcnt vmcnt(0)" ::: "memory")

    // prologue: pairs 0 and 1 in flight
    issue1(R0); issue1(R1); issue1(R2); issue1(R3);

    for (int t = 0; t < npairs; t += 2){
        // ---- pair t: regs R0,R1 -> bufs 0,1 ----
        if (t + 1 < npairs) WAIT_CUR(); else WAIT_ALL();
        __builtin_amdgcn_sched_barrier(0);
        commit1(R0, 0); commit1(R1, 1);
        if (t + 2 < npairs){ issue1(R0); issue1(R1); }   // pair t+2
        asm volatile("s_waitcnt lgkmcnt(0)" ::: "memory");
        __builtin_amdgcn_sched_barrier(0);
        __builtin_amdgcn_s_barrier();
        compute1(0); compute1(1);

        // ---- pair t+1: regs R2,R3 -> bufs 2,3 ----
        if (t + 2 < npairs) WAIT_CUR(); else WAIT_ALL();
        __builtin_amdgcn_sched_barrier(0);
        commit1(R2, 2); commit1(R3, 3);
        if (t + 3 < npairs){ issue1(R2); issue1(R3); }   // pair t+3
        asm volatile("s_waitcnt lgkmcnt(0)" ::: "memory");
        __builtin_amdgcn_sched_barrier(0);
        __builtin_amdgcn_s_barrier();
        compute1(2); compute1(3);
    }
    #undef WAIT_CUR
    #undef WAIT_ALL

    // epilogue: D rows m = q*4+r (pixels), cols n = ln (cout)
    #pragma unroll
    for (int i = 0; i < 2; i++){
        const int m0 = wm * 32 + i * 16 + q * 4;
        const int p = p0 + m0;
        #pragma unroll
        for (int j = 0; j < NJ; j++){
            const int n = nt0 + wn * BNh + j * 16 + ln;
            const float bv = bias[n];
            if (EPI == 0){
                #pragma unroll
                for (int r = 0; r < 4; r++){
                    float v = fmaxf(acc[i][j][r] + bv, 0.f);
                    obf[(size_t)(p + r) * ostride + n] = f2bf(v);
                }
            } else {
                f4v o;
                #pragma unroll
                for (int r = 0; r < 4; r++) o[r] = fmaxf(acc[i][j][r] + bv, 0.f);
                const int rem = rem0 + m0;
                *(f4v*)(of32 + (((size_t)b * Cout + n) << logHW) + rem) = o;
            }
        }
    }
}

// ============================================================
extern "C" void kernel_launch(void* const* d_in, const int* in_sizes, int n_in,
                              void* d_out, int out_size, void* d_ws, size_t ws_size,
                              hipStream_t stream){
    (void)in_sizes; (void)n_in; (void)out_size; (void)ws_size;

    const float* X[4][2];
    for (int s = 0; s < 4; s++)
        for (int l = 0; l < 2; l++)
            X[s][l] = (const float*)d_in[s * 2 + l];
    const float* Wg[2] = { (const float*)d_in[8],  (const float*)d_in[14] };
    const float* bg[2] = { (const float*)d_in[9],  (const float*)d_in[15] };
    const float* Wd[2] = { (const float*)d_in[10], (const float*)d_in[16] };
    const float* bd[2] = { (const float*)d_in[11], (const float*)d_in[17] };
    const float* Wc[2] = { (const float*)d_in[12], (const float*)d_in[18] };
    const float* bc[2] = { (const float*)d_in[13], (const float*)d_in[19] };
    float* out = (float*)d_out;

    // workspace layout (re-laid out so gz sits right after the 25 corr
    // slots -> ONE memset covers both):
    //   0        gmax (24 slots used)
    //   1024     zp   (3KB zeros)
    //   4096     corrbuf: 25 slots + gz (2 slots), 2MB region
    //   +2MB     newbuf / wtbuf alias (16.7MB)
    //   +16M     ginbuf (16.7MB)
    //   +16M     totbuf (25.2MB)
    char* ws = (char*)d_ws;
    unsigned* gmax = (unsigned*)ws;
    const void* zp = (const void*)(ws + 1024);
    float* corrbuf = (float*)(ws + 4096);
    float* newbuf  = (float*)(ws + 4096 + 2097152);
    unsigned short* wtbuf = (unsigned short*)newbuf;   // alias, disjoint lifetime
    unsigned short* ginbuf = (unsigned short*)(ws + 4096 + 2097152 + 16777216);
    unsigned short* totbuf = (unsigned short*)(ws + 4096 + 2097152 + 16777216 + 16777216);

    hipMemsetAsync(ws, 0, 4096, stream);

    const int Cs[2] = {256, 512};
    const int Hs[2] = {64, 32};
    const int logWs[2] = {6, 5};
    const int logHWs[2] = {12, 10};
    const size_t outOff[2] = {0, (size_t)4 * 256 * 4096};

    for (int l = 0; l < 2; l++){
        const int C = Cs[l], H = Hs[l], W = Hs[l], HW = H * W;
        const int logW = logWs[l], logHW = logHWs[l];
        const float* key = X[3][l];
        const int Mt = 4 * HW / 64;            // BM=64 tiles: l0=256, l1=64

        const int gx  = 4 * HW / 64;           // row-band tiles: {256, 64}
        const int S   = (l == 0) ? 2 : 8;      // c-split across grid.y -> 512 blocks
        const int CWc = C / (4 * S);           // channels per wave (corr/warp)
        const int CWg = (2 * C) / (4 * S);     // channels per wave (gate)

        float* gzbuf = corrbuf + ((size_t)4 * 25 << logHW);   // contiguous after corr

        for (int s = 0; s < 3; s++){
            const float* fr = X[s][l];
            unsigned* slot = gmax + (l * 3 + s);
            hipMemsetAsync(corrbuf, 0, (size_t)4 * 27 * HW * 4, stream);  // corr + gz
            corr_v2<<<dim3(gx, S), 256, 0, stream>>>(
                key, fr, corrbuf, C, CWc, H, W, logHW, logW);
            max_kernel<<<25 * 4 * HW / 256, 256, 0, stream>>>(corrbuf, slot);
            warp_v3<<<dim3(gx, S), 256, 0, stream>>>(
                fr, corrbuf, slot, newbuf, C, CWc, H, W, logHW, logW);
            gate_v2<<<dim3(gx, S), 256, 0, stream>>>(
                key, newbuf, Wg[l] + (size_t)s * 2 * (2 * C) * 9,
                gzbuf, C, CWg, H, W, logHW, logW);
            prep_gin<<<dim3(4 * HW / 64, 2 * C / 64), 256, 0, stream>>>(
                key, newbuf, gzbuf, bg[l] + (size_t)s * 2, ginbuf, C, HW);
            prep_w<<<dim3(C * 9, 2 * C / 256), 256, 0, stream>>>(
                Wd[l] + (size_t)s * C * 2 * C * 9, wtbuf, 2 * C);
            if (l == 0)
                conv_mfma<128, 0><<<dim3(Mt, C / 128), 256, 0, stream>>>(
                    ginbuf, wtbuf, bd[l] + s * C, totbuf + s * C, 3 * C,
                    nullptr, zp, 2 * C, C, H, W, logHW, logW);
            else
                conv_mfma<64, 0><<<dim3(Mt, C / 64), 256, 0, stream>>>(
                    ginbuf, wtbuf, bd[l] + s * C, totbuf + s * C, 3 * C,
                    nullptr, zp, 2 * C, C, H, W, logHW, logW);
        }
        prep_w<<<dim3(C * 9, 3 * C / 256), 256, 0, stream>>>(Wc[l], wtbuf, 3 * C);
        if (l == 0)
            conv_mfma<128, 1><<<dim3(Mt, 2), 256, 0, stream>>>(
                totbuf, wtbuf, bc[l], nullptr, 0,
                out + outOff[l], zp, 3 * C, C, H, W, logHW, logW);
        else
            conv_mfma<64, 1><<<dim3(Mt, 8), 256, 0, stream>>>(
                totbuf, wtbuf, bc[l], nullptr, 0,
                out + outOff[l], zp, 3 * C, C, H, W, logHW, logW);
    }
}

// Round 11
// 1640.660 us; speedup vs baseline: 1.2053x; 1.0793x over previous
//
#include <hip/hip_runtime.h>
#include <hip/hip_bf16.h>
#include <math.h>

#define PAD 2

typedef __attribute__((ext_vector_type(8))) short s8v;    // 8 bf16 = 4 VGPRs
typedef __attribute__((ext_vector_type(4))) float f4v;    // 4 fp32 acc

__device__ __forceinline__ f4v mfma16(s8v a, s8v b, f4v c){
    return __builtin_amdgcn_mfma_f32_16x16x32_bf16(a, b, c, 0, 0, 0);
}

__device__ __forceinline__ unsigned short f2bf(float f){
    unsigned u = __float_as_uint(f);
    unsigned r = u + 0x7FFFu + ((u >> 16) & 1u);
    return (unsigned short)(r >> 16);
}

// ---- ordered-uint encoding for float atomicMax ----
__device__ __forceinline__ unsigned f2o(float f){
    unsigned b = __float_as_uint(f);
    return (b & 0x80000000u) ? ~b : (b | 0x80000000u);
}
__device__ __forceinline__ float o2f(unsigned u){
    return __uint_as_float((u & 0x80000000u) ? (u & 0x7fffffffu) : ~u);
}

__device__ __forceinline__ float bperm(int adr, float v){
    return __uint_as_float((unsigned)__builtin_amdgcn_ds_bpermute(adr, (int)__float_as_uint(v)));
}

// ============================================================
// corr v3: r5 structure + higher c-split S (l0: 2->8, l1: 8->16)
// for TLP (latency-bound serial c-loop at 2 blocks/CU was the
// bottleneck) + unroll-2 on the c-loop for load ILP.
// ============================================================
__global__ __launch_bounds__(256)
void corr_v2(const float* __restrict__ key, const float* __restrict__ frame,
             float* __restrict__ corr,
             int C, int CW, int H, int W, int logHW, int logW){
    const int tid = threadIdx.x, lane = tid & 63, wv = tid >> 6;
    const int HW = 1 << logHW;
    const int p0 = blockIdx.x * 64;
    const int b  = p0 >> logHW;
    const int remL = (p0 & (HW - 1)) + lane;
    const int y = remL >> logW, x = remL & (W - 1);

    float m[25];
    #pragma unroll
    for (int t = 0; t < 25; t++){
        const int dy = t / 5 - 2, dx = t % 5 - 2;
        m[t] = (((unsigned)(y + dy) < (unsigned)H) &&
                ((unsigned)(x + dx) < (unsigned)W)) ? 1.f : 0.f;
    }
    int adr[4];
    const int dxs[4] = {-2, -1, 1, 2};
    #pragma unroll
    for (int i = 0; i < 4; i++) adr[i] = ((lane + dxs[i]) & 63) << 2;

    int roff[5];
    #pragma unroll
    for (int r = 0; r < 5; r++){
        const int dy = r - 2;
        roff[r] = ((unsigned)(y + dy) < (unsigned)H) ? dy * W : 0;
    }

    const int c0 = (blockIdx.y * 4 + wv) * CW;
    const float* kp = key   + (((size_t)b * C + c0) << logHW) + remL;
    const float* fp = frame + (((size_t)b * C + c0) << logHW) + remL;

    float acc[25];
    #pragma unroll
    for (int t = 0; t < 25; t++) acc[t] = 0.f;

    #pragma unroll 2
    for (int ci = 0; ci < CW; ci++){
        const float k = kp[0];
        float f[5];
        #pragma unroll
        for (int r = 0; r < 5; r++) f[r] = fp[roff[r]];
        #pragma unroll
        for (int r = 0; r < 5; r++){
            float v[5];
            v[0] = bperm(adr[0], f[r]);
            v[1] = bperm(adr[1], f[r]);
            v[2] = f[r];
            v[3] = bperm(adr[2], f[r]);
            v[4] = bperm(adr[3], f[r]);
            #pragma unroll
            for (int j = 0; j < 5; j++)
                acc[r * 5 + j] += k * (v[j] * m[r * 5 + j]);
        }
        kp += HW; fp += HW;
    }

    __shared__ float sacc[4][25][64];
    #pragma unroll
    for (int t = 0; t < 25; t++) sacc[wv][t][lane] = acc[t];
    __syncthreads();
    #pragma unroll
    for (int tg = 0; tg < 7; tg++){
        const int t = wv + tg * 4;
        if (t < 25){
            const float s = sacc[0][t][lane] + sacc[1][t][lane] +
                            sacc[2][t][lane] + sacc[3][t][lane];
            atomicAdd(corr + (((size_t)b * 25 + t) << logHW) + remL, s);
        }
    }
}

// ============================================================
// global max over the summed corr buffer (runs after corr_v2).
// ============================================================
__global__ void max_kernel(const float* __restrict__ corr, unsigned* __restrict__ gmax){
    float v = corr[(size_t)blockIdx.x * 256 + threadIdx.x];
    #pragma unroll
    for (int o = 32; o > 0; o >>= 1) v = fmaxf(v, __shfl_down(v, o));
    if ((threadIdx.x & 63) == 0) atomicMax(gmax, f2o(v));
}

// ============================================================
// warp v3 (fused softmax, verified r10) + higher S + unroll-2.
// ============================================================
__global__ __launch_bounds__(256)
void warp_v3(const float* __restrict__ frame, const float* __restrict__ corr,
             const unsigned* __restrict__ gmax, float* __restrict__ newf,
             int C, int CW, int H, int W, int logHW, int logW){
    const int tid = threadIdx.x, lane = tid & 63, wv = tid >> 6;
    const int HW = 1 << logHW;
    const int p0 = blockIdx.x * 64;
    const int b  = p0 >> logHW;
    const int remL = (p0 & (HW - 1)) + lane;
    const int y = remL >> logW, x = remL & (W - 1);

    int adr[4];
    const int dxs[4] = {-2, -1, 1, 2};
    #pragma unroll
    for (int i = 0; i < 4; i++) adr[i] = ((lane + dxs[i]) & 63) << 2;

    int roff[5];
    #pragma unroll
    for (int r = 0; r < 5; r++){
        const int dy = r - 2;
        roff[r] = ((unsigned)(y + dy) < (unsigned)H) ? dy * W : 0;
    }

    // in-register softmax over the 25 offsets
    const float scale = 20.f / o2f(*gmax);
    const float* cp = corr + (((size_t)b * 25) << logHW) + remL;
    float a[25]; float mx = -INFINITY;
    #pragma unroll
    for (int t = 0; t < 25; t++){
        a[t] = cp[(size_t)t << logHW] * scale;
        mx = fmaxf(mx, a[t]);
    }
    float ssum = 0.f;
    #pragma unroll
    for (int t = 0; t < 25; t++){ a[t] = expf(a[t] - mx); ssum += a[t]; }
    const float inv = 1.f / ssum;
    #pragma unroll
    for (int t = 0; t < 25; t++){
        const int dy = t / 5 - 2, dx = t % 5 - 2;
        const float mk = (((unsigned)(y + dy) < (unsigned)H) &&
                          ((unsigned)(x + dx) < (unsigned)W)) ? 1.f : 0.f;
        a[t] *= inv * mk;
    }

    const int c0 = (blockIdx.y * 4 + wv) * CW;
    const float* fp = frame + (((size_t)b * C + c0) << logHW) + remL;
    float*       op = newf  + (((size_t)b * C + c0) << logHW) + remL;

    #pragma unroll 2
    for (int ci = 0; ci < CW; ci++){
        float f[5];
        #pragma unroll
        for (int r = 0; r < 5; r++) f[r] = fp[roff[r]];
        float acc = 0.f;
        #pragma unroll
        for (int r = 0; r < 5; r++){
            float v[5];
            v[0] = bperm(adr[0], f[r]);
            v[1] = bperm(adr[1], f[r]);
            v[2] = f[r];
            v[3] = bperm(adr[2], f[r]);
            v[4] = bperm(adr[3], f[r]);
            #pragma unroll
            for (int j = 0; j < 5; j++)
                acc += a[r * 5 + j] * v[j];
        }
        op[0] = acc;
        fp += HW; op += HW;
    }
}

// ============================================================
// gate v2 (verified r5) + higher S + unroll-2.
// ============================================================
__global__ __launch_bounds__(256)
void gate_v2(const float* __restrict__ key, const float* __restrict__ newf,
             const float* __restrict__ Wg, float* __restrict__ gz,
             int C, int CW, int H, int W, int logHW, int logW){
    const int tid = threadIdx.x, lane = tid & 63, wv = tid >> 6;
    const int HW = 1 << logHW;
    const int p0 = blockIdx.x * 64;
    const int b  = p0 >> logHW;
    const int remL = (p0 & (HW - 1)) + lane;
    const int y = remL >> logW, x = remL & (W - 1);

    float m[9];
    #pragma unroll
    for (int t = 0; t < 9; t++){
        const int dy = t / 3 - 1, dx = t % 3 - 1;
        m[t] = (((unsigned)(y + dy) < (unsigned)H) &&
                ((unsigned)(x + dx) < (unsigned)W)) ? 1.f : 0.f;
    }
    const int adrL = ((lane - 1) & 63) << 2;
    const int adrR = ((lane + 1) & 63) << 2;

    int roff[3];
    #pragma unroll
    for (int r = 0; r < 3; r++){
        const int dy = r - 1;
        roff[r] = ((unsigned)(y + dy) < (unsigned)H) ? dy * W : 0;
    }

    const int c0 = (blockIdx.y * 4 + wv) * CW;   // u in [0, 2C); chunk never straddles C
    const float* base = (c0 < C)
        ? key  + (((size_t)b * C + c0)       << logHW)
        : newf + (((size_t)b * C + (c0 - C)) << logHW);
    const float* ip = base + remL;

    float z0 = 0.f, z1 = 0.f;
    #pragma unroll 2
    for (int ci = 0; ci < CW; ci++){
        const int u = c0 + ci;
        const float* w0 = Wg + (size_t)u * 9;
        const float* w1 = Wg + ((size_t)2 * C + u) * 9;
        float f[3];
        #pragma unroll
        for (int r = 0; r < 3; r++) f[r] = ip[roff[r]];
        #pragma unroll
        for (int r = 0; r < 3; r++){
            float v[3];
            v[0] = bperm(adrL, f[r]);
            v[1] = f[r];
            v[2] = bperm(adrR, f[r]);
            #pragma unroll
            for (int j = 0; j < 3; j++){
                const float val = v[j] * m[r * 3 + j];
                z0 += val * w0[r * 3 + j];
                z1 += val * w1[r * 3 + j];
            }
        }
        ip += HW;
    }

    __shared__ float sz[2][4][64];
    sz[0][wv][lane] = z0; sz[1][wv][lane] = z1;
    __syncthreads();
    if (wv < 2){
        const float s = sz[wv][0][lane] + sz[wv][1][lane] +
                        sz[wv][2][lane] + sz[wv][3][lane];
        atomicAdd(gz + ((size_t)b * 2 + wv) * HW + remL, s);
    }
}

// ============================================================
// prep_gin: NCHW fp32 (key,new) * sigmoid(gz+bg) -> NHWC bf16 gin
// ============================================================
__global__ void prep_gin(const float* __restrict__ key, const float* __restrict__ newf,
                         const float* __restrict__ g, const float* __restrict__ bg,
                         unsigned short* __restrict__ gin,
                         int C, int HW){
    __shared__ unsigned short tile[64][65];
    int tid = threadIdx.x;
    int pt0 = blockIdx.x * 64;
    int u0  = blockIdx.y * 64;
    int b   = pt0 / HW;
    int rem0 = pt0 - b * HW;
    const float* gb = g + (size_t)(b * 2) * HW;

    #pragma unroll
    for (int it = 0; it < 16; it++){
        int idx = it * 256 + tid;
        int ur = idx >> 6, pc = idx & 63;
        int u = u0 + ur; int rem = rem0 + pc;
        const float* src; int sel;
        if (u < C){ src = key  + ((size_t)b * C + u) * HW;       sel = 0; }
        else      { src = newf + ((size_t)b * C + (u - C)) * HW; sel = 1; }
        float zz = gb[(size_t)sel * HW + rem] + bg[sel];
        float gv = 1.f / (1.f + expf(-zz));
        float v = src[rem] * gv;
        tile[ur][pc] = f2bf(v);
    }
    __syncthreads();
    unsigned short* go = gin + (size_t)pt0 * (2 * C) + u0;
    #pragma unroll
    for (int it = 0; it < 16; it++){
        int idx = it * 256 + tid;
        int pr = idx >> 6, uc = idx & 63;
        go[(size_t)pr * (2 * C) + uc] = tile[uc][pr];
    }
}

// ============================================================
// prep_w: W[co][ci][t] fp32 -> Wt[co][t*Cin+ci] bf16
// ============================================================
__global__ void prep_w(const float* __restrict__ W, unsigned short* __restrict__ Wt,
                       int Cin){
    int ci = blockIdx.y * 256 + threadIdx.x;
    int bx = blockIdx.x;
    int co = bx / 9, t = bx - co * 9;
    Wt[(size_t)bx * Cin + ci] = f2bf(W[((size_t)co * Cin + ci) * 9 + t]);
}

// ============================================================
// conv_mfma v6 (verified 119-123us, UNTOUCHED): BM=64, 256-thread
// pair-step reg-staged pipeline, natural 2D grid.
// ============================================================
template<int BN, int EPI>
__global__ __launch_bounds__(256, 2)
void conv_mfma(const unsigned short* __restrict__ gin,
               const unsigned short* __restrict__ Wt,
               const float* __restrict__ bias,
               unsigned short* __restrict__ obf, int ostride,
               float* __restrict__ of32,
               const void* __restrict__ zp,
               int Cin, int Cout, int H, int W, int logHW, int logW)
{
    constexpr int BM = 64;
    constexpr int BNh = BN / 2;
    constexpr int NJ = BN / 32;
    __shared__ __align__(16) unsigned short sA[4][BM * 32];
    __shared__ __align__(16) unsigned short sB[4][BN * 32];

    const int tid = threadIdx.x;
    const int lane = tid & 63;
    const int wv = tid >> 6;
    const int wm = wv >> 1, wn = wv & 1;
    const int ln = lane & 15, q = lane >> 4;

    const int p0 = blockIdx.x * BM;
    const int b  = p0 >> logHW;
    const int rem0 = p0 - (b << logHW);

    // staging: row = tid>>2 (0..63); swizzled global chunk
    const int rowA0 = tid >> 2;
    const int gc8 = ((tid & 3) ^ ((tid >> 3) & 3)) * 8;    // element offset
    const int remA0 = rem0 + rowA0;
    const int yA0 = remA0 >> logW, xA0 = remA0 & (W - 1);
    const size_t pbase = ((size_t)b << logHW);

    const int nt0 = blockIdx.y * BN;
    const size_t Ktot = (size_t)9 * Cin;
    const unsigned short* wB0 = Wt + (size_t)(nt0 + rowA0) * Ktot + gc8;

    f4v acc[2][NJ];
    #pragma unroll
    for (int i = 0; i < 2; i++)
        #pragma unroll
        for (int j = 0; j < NJ; j++){ f4v z = {0.f, 0.f, 0.f, 0.f}; acc[i][j] = z; }

    const int cblocks = Cin >> 5;
    const int total = 9 * cblocks;       // 144/216/288/432 — always even
    const int npairs = total >> 1;       // 72/108/144/216 — always even

    // staging-cursor state (for the NEXT K-block to issue)
    int scb = 0;                                   // k-chunk within tap
    int st  = 0;                                   // tap index
    bool sv = (yA0 > 0) && (xA0 > 0);              // tap 0: dy=-1,dx=-1
    const unsigned short* sa  = gin + (pbase + remA0 + (-W - 1)) * Cin + gc8;
    const unsigned short* swb = wB0;               // +32 per issued K-block

    struct Regs { f4v a, b0, b1; };
    Regs R0, R1, R2, R3;

    auto issue1 = [&](Regs& r){
        r.a  = *(const f4v*)(sv ? (const void*)(sa + scb * 32) : zp);
        r.b0 = *(const f4v*)swb;
        if constexpr (BN == 128) r.b1 = *(const f4v*)(swb + (size_t)64 * Ktot);
        swb += 32;
        if (++scb == cblocks){
            scb = 0; ++st;
            const int dy = st / 3 - 1, dx = st - (st / 3) * 3 - 1;
            sv = ((unsigned)(yA0 + dy) < (unsigned)H) && ((unsigned)(xA0 + dx) < (unsigned)W);
            sa = gin + (pbase + remA0 + dy * W + dx) * Cin + gc8;
        }
    };
    auto commit1 = [&](const Regs& r, int buf){
        *(f4v*)((char*)sA[buf] + (size_t)tid * 16) = r.a;
        char* dB = (char*)sB[buf];
        *(f4v*)(dB + (size_t)tid * 16) = r.b0;
        if constexpr (BN == 128) *(f4v*)(dB + 4096 + (size_t)tid * 16) = r.b1;
    };

    const int rchunk = (q ^ ((ln >> 1) & 3)) * 8;   // swizzled read offset
    auto compute1 = [&](int buf){
        const unsigned short* A = sA[buf];
        const unsigned short* B = sB[buf];
        s8v af[2];
        #pragma unroll
        for (int i = 0; i < 2; i++)
            af[i] = *(const s8v*)(A + (wm * 32 + i * 16 + ln) * 32 + rchunk);
        __builtin_amdgcn_s_setprio(1);
        #pragma unroll
        for (int j = 0; j < NJ; j++){
            s8v bfr = *(const s8v*)(B + (wn * BNh + j * 16 + ln) * 32 + rchunk);
            #pragma unroll
            for (int i = 0; i < 2; i++)
                acc[i][j] = mfma16(af[i], bfr, acc[i][j]);
        }
        __builtin_amdgcn_s_setprio(0);
    };

    // vmcnt literal = loads per PAIR still in flight (BN==128 -> 6, else 4)
    #define WAIT_CUR()  do{ if constexpr (BN == 128) asm volatile("s_waitcnt vmcnt(6)" ::: "memory"); \
                            else                     asm volatile("s_waitcnt vmcnt(4)" ::: "memory"); }while(0)
    #define WAIT_ALL()  asm volatile("s_waitcnt vmcnt(0)" ::: "memory")

    // prologue: pairs 0 and 1 in flight
    issue1(R0); issue1(R1); issue1(R2); issue1(R3);

    for (int t = 0; t < npairs; t += 2){
        // ---- pair t: regs R0,R1 -> bufs 0,1 ----
        if (t + 1 < npairs) WAIT_CUR(); else WAIT_ALL();
        __builtin_amdgcn_sched_barrier(0);
        commit1(R0, 0); commit1(R1, 1);
        if (t + 2 < npairs){ issue1(R0); issue1(R1); }   // pair t+2
        asm volatile("s_waitcnt lgkmcnt(0)" ::: "memory");
        __builtin_amdgcn_sched_barrier(0);
        __builtin_amdgcn_s_barrier();
        compute1(0); compute1(1);

        // ---- pair t+1: regs R2,R3 -> bufs 2,3 ----
        if (t + 2 < npairs) WAIT_CUR(); else WAIT_ALL();
        __builtin_amdgcn_sched_barrier(0);
        commit1(R2, 2); commit1(R3, 3);
        if (t + 3 < npairs){ issue1(R2); issue1(R3); }   // pair t+3
        asm volatile("s_waitcnt lgkmcnt(0)" ::: "memory");
        __builtin_amdgcn_sched_barrier(0);
        __builtin_amdgcn_s_barrier();
        compute1(2); compute1(3);
    }
    #undef WAIT_CUR
    #undef WAIT_ALL

    // epilogue: D rows m = q*4+r (pixels), cols n = ln (cout)
    #pragma unroll
    for (int i = 0; i < 2; i++){
        const int m0 = wm * 32 + i * 16 + q * 4;
        const int p = p0 + m0;
        #pragma unroll
        for (int j = 0; j < NJ; j++){
            const int n = nt0 + wn * BNh + j * 16 + ln;
            const float bv = bias[n];
            if (EPI == 0){
                #pragma unroll
                for (int r = 0; r < 4; r++){
                    float v = fmaxf(acc[i][j][r] + bv, 0.f);
                    obf[(size_t)(p + r) * ostride + n] = f2bf(v);
                }
            } else {
                f4v o;
                #pragma unroll
                for (int r = 0; r < 4; r++) o[r] = fmaxf(acc[i][j][r] + bv, 0.f);
                const int rem = rem0 + m0;
                *(f4v*)(of32 + (((size_t)b * Cout + n) << logHW) + rem) = o;
            }
        }
    }
}

// ============================================================
extern "C" void kernel_launch(void* const* d_in, const int* in_sizes, int n_in,
                              void* d_out, int out_size, void* d_ws, size_t ws_size,
                              hipStream_t stream){
    (void)in_sizes; (void)n_in; (void)out_size; (void)ws_size;

    const float* X[4][2];
    for (int s = 0; s < 4; s++)
        for (int l = 0; l < 2; l++)
            X[s][l] = (const float*)d_in[s * 2 + l];
    const float* Wg[2] = { (const float*)d_in[8],  (const float*)d_in[14] };
    const float* bg[2] = { (const float*)d_in[9],  (const float*)d_in[15] };
    const float* Wd[2] = { (const float*)d_in[10], (const float*)d_in[16] };
    const float* bd[2] = { (const float*)d_in[11], (const float*)d_in[17] };
    const float* Wc[2] = { (const float*)d_in[12], (const float*)d_in[18] };
    const float* bc[2] = { (const float*)d_in[13], (const float*)d_in[19] };
    float* out = (float*)d_out;

    // workspace layout:
    //   0        gmax (24 slots used)
    //   1024     zp   (3KB zeros)
    //   4096     corrbuf: 25 slots + gz (2 slots), 2MB region
    //   +2MB     newbuf / wtbuf alias (16.7MB)
    //   +16M     ginbuf (16.7MB)
    //   +16M     totbuf (25.2MB)
    char* ws = (char*)d_ws;
    unsigned* gmax = (unsigned*)ws;
    const void* zp = (const void*)(ws + 1024);
    float* corrbuf = (float*)(ws + 4096);
    float* newbuf  = (float*)(ws + 4096 + 2097152);
    unsigned short* wtbuf = (unsigned short*)newbuf;   // alias, disjoint lifetime
    unsigned short* ginbuf = (unsigned short*)(ws + 4096 + 2097152 + 16777216);
    unsigned short* totbuf = (unsigned short*)(ws + 4096 + 2097152 + 16777216 + 16777216);

    hipMemsetAsync(ws, 0, 4096, stream);

    const int Cs[2] = {256, 512};
    const int Hs[2] = {64, 32};
    const int logWs[2] = {6, 5};
    const int logHWs[2] = {12, 10};
    const size_t outOff[2] = {0, (size_t)4 * 256 * 4096};

    for (int l = 0; l < 2; l++){
        const int C = Cs[l], H = Hs[l], W = Hs[l], HW = H * W;
        const int logW = logWs[l], logHW = logHWs[l];
        const float* key = X[3][l];
        const int Mt = 4 * HW / 64;            // BM=64 tiles: l0=256, l1=64

        const int gx  = 4 * HW / 64;           // row-band tiles: {256, 64}
        const int S   = (l == 0) ? 8 : 16;     // c-split (TLP): l0 2048, l1 1024 blocks
        const int CWc = C / (4 * S);           // channels per wave (corr/warp): 8
        const int CWg = (2 * C) / (4 * S);     // channels per wave (gate): 16

        float* gzbuf = corrbuf + ((size_t)4 * 25 << logHW);   // contiguous after corr

        for (int s = 0; s < 3; s++){
            const float* fr = X[s][l];
            unsigned* slot = gmax + (l * 3 + s);
            hipMemsetAsync(corrbuf, 0, (size_t)4 * 27 * HW * 4, stream);  // corr + gz
            corr_v2<<<dim3(gx, S), 256, 0, stream>>>(
                key, fr, corrbuf, C, CWc, H, W, logHW, logW);
            max_kernel<<<25 * 4 * HW / 256, 256, 0, stream>>>(corrbuf, slot);
            warp_v3<<<dim3(gx, S), 256, 0, stream>>>(
                fr, corrbuf, slot, newbuf, C, CWc, H, W, logHW, logW);
            gate_v2<<<dim3(gx, S), 256, 0, stream>>>(
                key, newbuf, Wg[l] + (size_t)s * 2 * (2 * C) * 9,
                gzbuf, C, CWg, H, W, logHW, logW);
            prep_gin<<<dim3(4 * HW / 64, 2 * C / 64), 256, 0, stream>>>(
                key, newbuf, gzbuf, bg[l] + (size_t)s * 2, ginbuf, C, HW);
            prep_w<<<dim3(C * 9, 2 * C / 256), 256, 0, stream>>>(
                Wd[l] + (size_t)s * C * 2 * C * 9, wtbuf, 2 * C);
            if (l == 0)
                conv_mfma<128, 0><<<dim3(Mt, C / 128), 256, 0, stream>>>(
                    ginbuf, wtbuf, bd[l] + s * C, totbuf + s * C, 3 * C,
                    nullptr, zp, 2 * C, C, H, W, logHW, logW);
            else
                conv_mfma<64, 0><<<dim3(Mt, C / 64), 256, 0, stream>>>(
                    ginbuf, wtbuf, bd[l] + s * C, totbuf + s * C, 3 * C,
                    nullptr, zp, 2 * C, C, H, W, logHW, logW);
        }
        prep_w<<<dim3(C * 9, 3 * C / 256), 256, 0, stream>>>(Wc[l], wtbuf, 3 * C);
        if (l == 0)
            conv_mfma<128, 1><<<dim3(Mt, 2), 256, 0, stream>>>(
                totbuf, wtbuf, bc[l], nullptr, 0,
                out + outOff[l], zp, 3 * C, C, H, W, logHW, logW);
        else
            conv_mfma<64, 1><<<dim3(Mt, 8), 256, 0, stream>>>(
                totbuf, wtbuf, bc[l], nullptr, 0,
                out + outOff[l], zp, 3 * C, C, H, W, logHW, logW);
    }
}

// Round 12
// 1563.859 us; speedup vs baseline: 1.2645x; 1.0491x over previous
//
#include <hip/hip_runtime.h>
#include <hip/hip_bf16.h>
#include <math.h>

#define PAD 2

typedef __attribute__((ext_vector_type(8))) short s8v;    // 8 bf16 = 4 VGPRs
typedef __attribute__((ext_vector_type(4))) float f4v;    // 4 fp32 acc

__device__ __forceinline__ f4v mfma16(s8v a, s8v b, f4v c){
    return __builtin_amdgcn_mfma_f32_16x16x32_bf16(a, b, c, 0, 0, 0);
}

__device__ __forceinline__ unsigned short f2bf(float f){
    unsigned u = __float_as_uint(f);
    unsigned r = u + 0x7FFFu + ((u >> 16) & 1u);
    return (unsigned short)(r >> 16);
}

// ---- ordered-uint encoding for float atomicMax ----
__device__ __forceinline__ unsigned f2o(float f){
    unsigned b = __float_as_uint(f);
    return (b & 0x80000000u) ? ~b : (b | 0x80000000u);
}
__device__ __forceinline__ float o2f(unsigned u){
    return __uint_as_float((u & 0x80000000u) ? (u & 0x7fffffffu) : ~u);
}

__device__ __forceinline__ float bperm(int adr, float v){
    return __uint_as_float((unsigned)__builtin_amdgcn_ds_bpermute(adr, (int)__float_as_uint(v)));
}

// ============================================================
// corr v3: r11 body (verified) + grid.z = time-step s. fr and the
// corr region are selected by blockIdx.z (stride sCorr floats).
// Batching 3 s-steps into one launch cuts dispatch count and
// triples blocks/launch (tail-effect amortization).
// ============================================================
__global__ __launch_bounds__(256)
void corr_v3(const float* __restrict__ key, const float* __restrict__ f0,
             const float* __restrict__ f1, const float* __restrict__ f2,
             float* __restrict__ corr,
             int C, int CW, int H, int W, int logHW, int logW, int sCorr){
    const int tid = threadIdx.x, lane = tid & 63, wv = tid >> 6;
    const int z = blockIdx.z;
    const float* frame = (z == 0) ? f0 : ((z == 1) ? f1 : f2);
    corr += (size_t)z * sCorr;

    const int HW = 1 << logHW;
    const int p0 = blockIdx.x * 64;
    const int b  = p0 >> logHW;
    const int remL = (p0 & (HW - 1)) + lane;
    const int y = remL >> logW, x = remL & (W - 1);

    float m[25];
    #pragma unroll
    for (int t = 0; t < 25; t++){
        const int dy = t / 5 - 2, dx = t % 5 - 2;
        m[t] = (((unsigned)(y + dy) < (unsigned)H) &&
                ((unsigned)(x + dx) < (unsigned)W)) ? 1.f : 0.f;
    }
    int adr[4];
    const int dxs[4] = {-2, -1, 1, 2};
    #pragma unroll
    for (int i = 0; i < 4; i++) adr[i] = ((lane + dxs[i]) & 63) << 2;

    int roff[5];
    #pragma unroll
    for (int r = 0; r < 5; r++){
        const int dy = r - 2;
        roff[r] = ((unsigned)(y + dy) < (unsigned)H) ? dy * W : 0;
    }

    const int c0 = (blockIdx.y * 4 + wv) * CW;
    const float* kp = key   + (((size_t)b * C + c0) << logHW) + remL;
    const float* fp = frame + (((size_t)b * C + c0) << logHW) + remL;

    float acc[25];
    #pragma unroll
    for (int t = 0; t < 25; t++) acc[t] = 0.f;

    #pragma unroll 2
    for (int ci = 0; ci < CW; ci++){
        const float k = kp[0];
        float f[5];
        #pragma unroll
        for (int r = 0; r < 5; r++) f[r] = fp[roff[r]];
        #pragma unroll
        for (int r = 0; r < 5; r++){
            float v[5];
            v[0] = bperm(adr[0], f[r]);
            v[1] = bperm(adr[1], f[r]);
            v[2] = f[r];
            v[3] = bperm(adr[2], f[r]);
            v[4] = bperm(adr[3], f[r]);
            #pragma unroll
            for (int j = 0; j < 5; j++)
                acc[r * 5 + j] += k * (v[j] * m[r * 5 + j]);
        }
        kp += HW; fp += HW;
    }

    __shared__ float sacc[4][25][64];
    #pragma unroll
    for (int t = 0; t < 25; t++) sacc[wv][t][lane] = acc[t];
    __syncthreads();
    #pragma unroll
    for (int tg = 0; tg < 7; tg++){
        const int t = wv + tg * 4;
        if (t < 25){
            const float s = sacc[0][t][lane] + sacc[1][t][lane] +
                            sacc[2][t][lane] + sacc[3][t][lane];
            atomicAdd(corr + (((size_t)b * 25 + t) << logHW) + remL, s);
        }
    }
}

// ============================================================
// max over 25 corr slots; grid.y = time-step s.
// ============================================================
__global__ void max3_kernel(const float* __restrict__ corr, unsigned* __restrict__ gmax,
                            int sCorr){
    const int z = blockIdx.y;
    float v = corr[(size_t)z * sCorr + (size_t)blockIdx.x * 256 + threadIdx.x];
    #pragma unroll
    for (int o = 32; o > 0; o >>= 1) v = fmaxf(v, __shfl_down(v, o));
    if ((threadIdx.x & 63) == 0) atomicMax(gmax + z, f2o(v));
}

// ============================================================
// warp v4: fused softmax (verified r10/r11) + grid.z = s.
// ============================================================
__global__ __launch_bounds__(256)
void warp_v4(const float* __restrict__ f0, const float* __restrict__ f1,
             const float* __restrict__ f2, const float* __restrict__ corr,
             const unsigned* __restrict__ gmax, float* __restrict__ newf,
             int C, int CW, int H, int W, int logHW, int logW,
             int sCorr, int sNew){
    const int tid = threadIdx.x, lane = tid & 63, wv = tid >> 6;
    const int z = blockIdx.z;
    const float* frame = (z == 0) ? f0 : ((z == 1) ? f1 : f2);

    const int HW = 1 << logHW;
    const int p0 = blockIdx.x * 64;
    const int b  = p0 >> logHW;
    const int remL = (p0 & (HW - 1)) + lane;
    const int y = remL >> logW, x = remL & (W - 1);

    int adr[4];
    const int dxs[4] = {-2, -1, 1, 2};
    #pragma unroll
    for (int i = 0; i < 4; i++) adr[i] = ((lane + dxs[i]) & 63) << 2;

    int roff[5];
    #pragma unroll
    for (int r = 0; r < 5; r++){
        const int dy = r - 2;
        roff[r] = ((unsigned)(y + dy) < (unsigned)H) ? dy * W : 0;
    }

    // in-register softmax over the 25 offsets
    const float scale = 20.f / o2f(gmax[z]);
    const float* cp = corr + (size_t)z * sCorr + (((size_t)b * 25) << logHW) + remL;
    float a[25]; float mx = -INFINITY;
    #pragma unroll
    for (int t = 0; t < 25; t++){
        a[t] = cp[(size_t)t << logHW] * scale;
        mx = fmaxf(mx, a[t]);
    }
    float ssum = 0.f;
    #pragma unroll
    for (int t = 0; t < 25; t++){ a[t] = expf(a[t] - mx); ssum += a[t]; }
    const float inv = 1.f / ssum;
    #pragma unroll
    for (int t = 0; t < 25; t++){
        const int dy = t / 5 - 2, dx = t % 5 - 2;
        const float mk = (((unsigned)(y + dy) < (unsigned)H) &&
                          ((unsigned)(x + dx) < (unsigned)W)) ? 1.f : 0.f;
        a[t] *= inv * mk;
    }

    const int c0 = (blockIdx.y * 4 + wv) * CW;
    const float* fp = frame + (((size_t)b * C + c0) << logHW) + remL;
    float*       op = newf + (size_t)z * sNew + (((size_t)b * C + c0) << logHW) + remL;

    #pragma unroll 2
    for (int ci = 0; ci < CW; ci++){
        float f[5];
        #pragma unroll
        for (int r = 0; r < 5; r++) f[r] = fp[roff[r]];
        float acc = 0.f;
        #pragma unroll
        for (int r = 0; r < 5; r++){
            float v[5];
            v[0] = bperm(adr[0], f[r]);
            v[1] = bperm(adr[1], f[r]);
            v[2] = f[r];
            v[3] = bperm(adr[2], f[r]);
            v[4] = bperm(adr[3], f[r]);
            #pragma unroll
            for (int j = 0; j < 5; j++)
                acc += a[r * 5 + j] * v[j];
        }
        op[0] = acc;
        fp += HW; op += HW;
    }
}

// ============================================================
// gate v3: verified r5/r11 body + grid.z = s (newf/Wg/gz strided).
// ============================================================
__global__ __launch_bounds__(256)
void gate_v3(const float* __restrict__ key, const float* __restrict__ newf,
             const float* __restrict__ Wg, float* __restrict__ gz,
             int C, int CW, int H, int W, int logHW, int logW,
             int sNew, int sCorr, int wgStep){
    const int tid = threadIdx.x, lane = tid & 63, wv = tid >> 6;
    const int z = blockIdx.z;
    const float* nf = newf + (size_t)z * sNew;
    const float* wg = Wg + (size_t)z * wgStep;
    float* gzp = gz + (size_t)z * sCorr;

    const int HW = 1 << logHW;
    const int p0 = blockIdx.x * 64;
    const int b  = p0 >> logHW;
    const int remL = (p0 & (HW - 1)) + lane;
    const int y = remL >> logW, x = remL & (W - 1);

    float m[9];
    #pragma unroll
    for (int t = 0; t < 9; t++){
        const int dy = t / 3 - 1, dx = t % 3 - 1;
        m[t] = (((unsigned)(y + dy) < (unsigned)H) &&
                ((unsigned)(x + dx) < (unsigned)W)) ? 1.f : 0.f;
    }
    const int adrL = ((lane - 1) & 63) << 2;
    const int adrR = ((lane + 1) & 63) << 2;

    int roff[3];
    #pragma unroll
    for (int r = 0; r < 3; r++){
        const int dy = r - 1;
        roff[r] = ((unsigned)(y + dy) < (unsigned)H) ? dy * W : 0;
    }

    const int c0 = (blockIdx.y * 4 + wv) * CW;   // u in [0, 2C); chunk never straddles C
    const float* base = (c0 < C)
        ? key + (((size_t)b * C + c0)       << logHW)
        : nf  + (((size_t)b * C + (c0 - C)) << logHW);
    const float* ip = base + remL;

    float z0 = 0.f, z1 = 0.f;
    #pragma unroll 2
    for (int ci = 0; ci < CW; ci++){
        const int u = c0 + ci;
        const float* w0 = wg + (size_t)u * 9;
        const float* w1 = wg + ((size_t)2 * C + u) * 9;
        float f[3];
        #pragma unroll
        for (int r = 0; r < 3; r++) f[r] = ip[roff[r]];
        #pragma unroll
        for (int r = 0; r < 3; r++){
            float v[3];
            v[0] = bperm(adrL, f[r]);
            v[1] = f[r];
            v[2] = bperm(adrR, f[r]);
            #pragma unroll
            for (int j = 0; j < 3; j++){
                const float val = v[j] * m[r * 3 + j];
                z0 += val * w0[r * 3 + j];
                z1 += val * w1[r * 3 + j];
            }
        }
        ip += HW;
    }

    __shared__ float sz[2][4][64];
    sz[0][wv][lane] = z0; sz[1][wv][lane] = z1;
    __syncthreads();
    if (wv < 2){
        const float s = sz[wv][0][lane] + sz[wv][1][lane] +
                        sz[wv][2][lane] + sz[wv][3][lane];
        atomicAdd(gzp + ((size_t)b * 2 + wv) * HW + remL, s);
    }
}

// ============================================================
// prep_gin: NCHW fp32 (key,new) * sigmoid(gz+bg) -> NHWC bf16 gin
// ============================================================
__global__ void prep_gin(const float* __restrict__ key, const float* __restrict__ newf,
                         const float* __restrict__ g, const float* __restrict__ bg,
                         unsigned short* __restrict__ gin,
                         int C, int HW){
    __shared__ unsigned short tile[64][65];
    int tid = threadIdx.x;
    int pt0 = blockIdx.x * 64;
    int u0  = blockIdx.y * 64;
    int b   = pt0 / HW;
    int rem0 = pt0 - b * HW;
    const float* gb = g + (size_t)(b * 2) * HW;

    #pragma unroll
    for (int it = 0; it < 16; it++){
        int idx = it * 256 + tid;
        int ur = idx >> 6, pc = idx & 63;
        int u = u0 + ur; int rem = rem0 + pc;
        const float* src; int sel;
        if (u < C){ src = key  + ((size_t)b * C + u) * HW;       sel = 0; }
        else      { src = newf + ((size_t)b * C + (u - C)) * HW; sel = 1; }
        float zz = gb[(size_t)sel * HW + rem] + bg[sel];
        float gv = 1.f / (1.f + expf(-zz));
        float v = src[rem] * gv;
        tile[ur][pc] = f2bf(v);
    }
    __syncthreads();
    unsigned short* go = gin + (size_t)pt0 * (2 * C) + u0;
    #pragma unroll
    for (int it = 0; it < 16; it++){
        int idx = it * 256 + tid;
        int pr = idx >> 6, uc = idx & 63;
        go[(size_t)pr * (2 * C) + uc] = tile[uc][pr];
    }
}

// ============================================================
// prep_w: W[co][ci][t] fp32 -> Wt[co][t*Cin+ci] bf16
// ============================================================
__global__ void prep_w(const float* __restrict__ W, unsigned short* __restrict__ Wt,
                       int Cin){
    int ci = blockIdx.y * 256 + threadIdx.x;
    int bx = blockIdx.x;
    int co = bx / 9, t = bx - co * 9;
    Wt[(size_t)bx * Cin + ci] = f2bf(W[((size_t)co * Cin + ci) * 9 + t]);
}

// ============================================================
// conv_mfma v6 (verified 119-123us, UNTOUCHED): BM=64, 256-thread
// pair-step reg-staged pipeline, natural 2D grid.
// ============================================================
template<int BN, int EPI>
__global__ __launch_bounds__(256, 2)
void conv_mfma(const unsigned short* __restrict__ gin,
               const unsigned short* __restrict__ Wt,
               const float* __restrict__ bias,
               unsigned short* __restrict__ obf, int ostride,
               float* __restrict__ of32,
               const void* __restrict__ zp,
               int Cin, int Cout, int H, int W, int logHW, int logW)
{
    constexpr int BM = 64;
    constexpr int BNh = BN / 2;
    constexpr int NJ = BN / 32;
    __shared__ __align__(16) unsigned short sA[4][BM * 32];
    __shared__ __align__(16) unsigned short sB[4][BN * 32];

    const int tid = threadIdx.x;
    const int lane = tid & 63;
    const int wv = tid >> 6;
    const int wm = wv >> 1, wn = wv & 1;
    const int ln = lane & 15, q = lane >> 4;

    const int p0 = blockIdx.x * BM;
    const int b  = p0 >> logHW;
    const int rem0 = p0 - (b << logHW);

    // staging: row = tid>>2 (0..63); swizzled global chunk
    const int rowA0 = tid >> 2;
    const int gc8 = ((tid & 3) ^ ((tid >> 3) & 3)) * 8;    // element offset
    const int remA0 = rem0 + rowA0;
    const int yA0 = remA0 >> logW, xA0 = remA0 & (W - 1);
    const size_t pbase = ((size_t)b << logHW);

    const int nt0 = blockIdx.y * BN;
    const size_t Ktot = (size_t)9 * Cin;
    const unsigned short* wB0 = Wt + (size_t)(nt0 + rowA0) * Ktot + gc8;

    f4v acc[2][NJ];
    #pragma unroll
    for (int i = 0; i < 2; i++)
        #pragma unroll
        for (int j = 0; j < NJ; j++){ f4v z = {0.f, 0.f, 0.f, 0.f}; acc[i][j] = z; }

    const int cblocks = Cin >> 5;
    const int total = 9 * cblocks;       // 144/216/288/432 — always even
    const int npairs = total >> 1;       // 72/108/144/216 — always even

    // staging-cursor state (for the NEXT K-block to issue)
    int scb = 0;                                   // k-chunk within tap
    int st  = 0;                                   // tap index
    bool sv = (yA0 > 0) && (xA0 > 0);              // tap 0: dy=-1,dx=-1
    const unsigned short* sa  = gin + (pbase + remA0 + (-W - 1)) * Cin + gc8;
    const unsigned short* swb = wB0;               // +32 per issued K-block

    struct Regs { f4v a, b0, b1; };
    Regs R0, R1, R2, R3;

    auto issue1 = [&](Regs& r){
        r.a  = *(const f4v*)(sv ? (const void*)(sa + scb * 32) : zp);
        r.b0 = *(const f4v*)swb;
        if constexpr (BN == 128) r.b1 = *(const f4v*)(swb + (size_t)64 * Ktot);
        swb += 32;
        if (++scb == cblocks){
            scb = 0; ++st;
            const int dy = st / 3 - 1, dx = st - (st / 3) * 3 - 1;
            sv = ((unsigned)(yA0 + dy) < (unsigned)H) && ((unsigned)(xA0 + dx) < (unsigned)W);
            sa = gin + (pbase + remA0 + dy * W + dx) * Cin + gc8;
        }
    };
    auto commit1 = [&](const Regs& r, int buf){
        *(f4v*)((char*)sA[buf] + (size_t)tid * 16) = r.a;
        char* dB = (char*)sB[buf];
        *(f4v*)(dB + (size_t)tid * 16) = r.b0;
        if constexpr (BN == 128) *(f4v*)(dB + 4096 + (size_t)tid * 16) = r.b1;
    };

    const int rchunk = (q ^ ((ln >> 1) & 3)) * 8;   // swizzled read offset
    auto compute1 = [&](int buf){
        const unsigned short* A = sA[buf];
        const unsigned short* B = sB[buf];
        s8v af[2];
        #pragma unroll
        for (int i = 0; i < 2; i++)
            af[i] = *(const s8v*)(A + (wm * 32 + i * 16 + ln) * 32 + rchunk);
        __builtin_amdgcn_s_setprio(1);
        #pragma unroll
        for (int j = 0; j < NJ; j++){
            s8v bfr = *(const s8v*)(B + (wn * BNh + j * 16 + ln) * 32 + rchunk);
            #pragma unroll
            for (int i = 0; i < 2; i++)
                acc[i][j] = mfma16(af[i], bfr, acc[i][j]);
        }
        __builtin_amdgcn_s_setprio(0);
    };

    // vmcnt literal = loads per PAIR still in flight (BN==128 -> 6, else 4)
    #define WAIT_CUR()  do{ if constexpr (BN == 128) asm volatile("s_waitcnt vmcnt(6)" ::: "memory"); \
                            else                     asm volatile("s_waitcnt vmcnt(4)" ::: "memory"); }while(0)
    #define WAIT_ALL()  asm volatile("s_waitcnt vmcnt(0)" ::: "memory")

    // prologue: pairs 0 and 1 in flight
    issue1(R0); issue1(R1); issue1(R2); issue1(R3);

    for (int t = 0; t < npairs; t += 2){
        // ---- pair t: regs R0,R1 -> bufs 0,1 ----
        if (t + 1 < npairs) WAIT_CUR(); else WAIT_ALL();
        __builtin_amdgcn_sched_barrier(0);
        commit1(R0, 0); commit1(R1, 1);
        if (t + 2 < npairs){ issue1(R0); issue1(R1); }   // pair t+2
        asm volatile("s_waitcnt lgkmcnt(0)" ::: "memory");
        __builtin_amdgcn_sched_barrier(0);
        __builtin_amdgcn_s_barrier();
        compute1(0); compute1(1);

        // ---- pair t+1: regs R2,R3 -> bufs 2,3 ----
        if (t + 2 < npairs) WAIT_CUR(); else WAIT_ALL();
        __builtin_amdgcn_sched_barrier(0);
        commit1(R2, 2); commit1(R3, 3);
        if (t + 3 < npairs){ issue1(R2); issue1(R3); }   // pair t+3
        asm volatile("s_waitcnt lgkmcnt(0)" ::: "memory");
        __builtin_amdgcn_sched_barrier(0);
        __builtin_amdgcn_s_barrier();
        compute1(2); compute1(3);
    }
    #undef WAIT_CUR
    #undef WAIT_ALL

    // epilogue: D rows m = q*4+r (pixels), cols n = ln (cout)
    #pragma unroll
    for (int i = 0; i < 2; i++){
        const int m0 = wm * 32 + i * 16 + q * 4;
        const int p = p0 + m0;
        #pragma unroll
        for (int j = 0; j < NJ; j++){
            const int n = nt0 + wn * BNh + j * 16 + ln;
            const float bv = bias[n];
            if (EPI == 0){
                #pragma unroll
                for (int r = 0; r < 4; r++){
                    float v = fmaxf(acc[i][j][r] + bv, 0.f);
                    obf[(size_t)(p + r) * ostride + n] = f2bf(v);
                }
            } else {
                f4v o;
                #pragma unroll
                for (int r = 0; r < 4; r++) o[r] = fmaxf(acc[i][j][r] + bv, 0.f);
                const int rem = rem0 + m0;
                *(f4v*)(of32 + (((size_t)b * Cout + n) << logHW) + rem) = o;
            }
        }
    }
}

// ============================================================
extern "C" void kernel_launch(void* const* d_in, const int* in_sizes, int n_in,
                              void* d_out, int out_size, void* d_ws, size_t ws_size,
                              hipStream_t stream){
    (void)in_sizes; (void)n_in; (void)out_size;

    const float* X[4][2];
    for (int s = 0; s < 4; s++)
        for (int l = 0; l < 2; l++)
            X[s][l] = (const float*)d_in[s * 2 + l];
    const float* Wg[2] = { (const float*)d_in[8],  (const float*)d_in[14] };
    const float* bg[2] = { (const float*)d_in[9],  (const float*)d_in[15] };
    const float* Wd[2] = { (const float*)d_in[10], (const float*)d_in[16] };
    const float* bd[2] = { (const float*)d_in[11], (const float*)d_in[17] };
    const float* Wc[2] = { (const float*)d_in[12], (const float*)d_in[18] };
    const float* bc[2] = { (const float*)d_in[13], (const float*)d_in[19] };
    float* out = (float*)d_out;

    // ---- batched (grid.z=3) layout needs ~107MB: gate on ws_size ----
    //   4096            gmax + zp
    //   corr3: 3 x 108*HW floats (25 corr slots + 2 gz + pad... =108/4=27 per b)
    //   new3 : 3 x 4*C*HW floats
    //   wt   : 14.2MB  (l1 Wc)
    //   gin  : 16.8MB
    //   tot  : 25.2MB
    const size_t NEED = 111742976ULL;
    const bool big = (ws_size >= NEED);

    char* ws = (char*)d_ws;
    unsigned* gmax = (unsigned*)ws;
    const void* zp = (const void*)(ws + 1024);

    float* corrR; float* newR; unsigned short* wtbuf;
    unsigned short* ginbuf; unsigned short* totbuf;
    if (big){
        corrR = (float*)(ws + 4096);
        newR  = (float*)(ws + 4096 + 5308416);
        wtbuf = (unsigned short*)(ws + 4096 + 5308416 + 50331648);
        ginbuf= (unsigned short*)(ws + 4096 + 5308416 + 50331648 + 14155776);
        totbuf= (unsigned short*)(ws + 4096 + 5308416 + 50331648 + 14155776 + 16777216);
    } else {
        // r11 layout: wtbuf aliases the (single) new buffer
        corrR = (float*)(ws + 4096);
        newR  = (float*)(ws + 4096 + 2097152);
        wtbuf = (unsigned short*)newR;
        ginbuf= (unsigned short*)(ws + 4096 + 2097152 + 16777216);
        totbuf= (unsigned short*)(ws + 4096 + 2097152 + 16777216 + 16777216);
    }

    hipMemsetAsync(ws, 0, 4096, stream);

    const int Cs[2] = {256, 512};
    const int Hs[2] = {64, 32};
    const int logWs[2] = {6, 5};
    const int logHWs[2] = {12, 10};
    const size_t outOff[2] = {0, (size_t)4 * 256 * 4096};

    for (int l = 0; l < 2; l++){
        const int C = Cs[l], H = Hs[l], W = Hs[l], HW = H * W;
        const int logW = logWs[l], logHW = logHWs[l];
        const float* key = X[3][l];
        const int Mt = 4 * HW / 64;            // BM=64 tiles: l0=256, l1=64

        const int gx  = 4 * HW / 64;           // row-band tiles: {256, 64}
        const int S   = (l == 0) ? 8 : 16;     // c-split (TLP)
        const int CWc = C / (4 * S);           // channels per wave (corr/warp): 8
        const int CWg = (2 * C) / (4 * S);     // channels per wave (gate): 16

        const int sCorr = 108 << logHW;        // floats per s (25+2 slots, b=4)
        const int sNew  = (4 * C) << logHW;    // floats per s
        const int wgStep = 2 * (2 * C) * 9;

        if (big){
            float* gzb = corrR + (((size_t)100) << logHW);   // gz = corr + 25 slots
            hipMemsetAsync(corrR, 0, (size_t)3 * sCorr * 4, stream);
            corr_v3<<<dim3(gx, S, 3), 256, 0, stream>>>(
                key, X[0][l], X[1][l], X[2][l], corrR, C, CWc, H, W, logHW, logW, sCorr);
            max3_kernel<<<dim3(25 * 4 * HW / 256, 3), 256, 0, stream>>>(
                corrR, gmax + l * 3, sCorr);
            warp_v4<<<dim3(gx, S, 3), 256, 0, stream>>>(
                X[0][l], X[1][l], X[2][l], corrR, gmax + l * 3, newR,
                C, CWc, H, W, logHW, logW, sCorr, sNew);
            gate_v3<<<dim3(gx, S, 3), 256, 0, stream>>>(
                key, newR, Wg[l], gzb, C, CWg, H, W, logHW, logW, sNew, sCorr, wgStep);
            for (int s = 0; s < 3; s++){
                prep_gin<<<dim3(4 * HW / 64, 2 * C / 64), 256, 0, stream>>>(
                    key, newR + (size_t)s * sNew, gzb + (size_t)s * sCorr,
                    bg[l] + (size_t)s * 2, ginbuf, C, HW);
                prep_w<<<dim3(C * 9, 2 * C / 256), 256, 0, stream>>>(
                    Wd[l] + (size_t)s * C * 2 * C * 9, wtbuf, 2 * C);
                if (l == 0)
                    conv_mfma<128, 0><<<dim3(Mt, C / 128), 256, 0, stream>>>(
                        ginbuf, wtbuf, bd[l] + s * C, totbuf + s * C, 3 * C,
                        nullptr, zp, 2 * C, C, H, W, logHW, logW);
                else
                    conv_mfma<64, 0><<<dim3(Mt, C / 64), 256, 0, stream>>>(
                        ginbuf, wtbuf, bd[l] + s * C, totbuf + s * C, 3 * C,
                        nullptr, zp, 2 * C, C, H, W, logHW, logW);
            }
        } else {
            float* gzb = corrR + (((size_t)100) << logHW);
            for (int s = 0; s < 3; s++){
                const float* fr = X[s][l];
                unsigned* slot = gmax + (l * 3 + s);
                hipMemsetAsync(corrR, 0, (size_t)sCorr * 4, stream);
                corr_v3<<<dim3(gx, S, 1), 256, 0, stream>>>(
                    key, fr, fr, fr, corrR, C, CWc, H, W, logHW, logW, sCorr);
                max3_kernel<<<dim3(25 * 4 * HW / 256, 1), 256, 0, stream>>>(
                    corrR, slot, sCorr);
                warp_v4<<<dim3(gx, S, 1), 256, 0, stream>>>(
                    fr, fr, fr, corrR, slot, newR,
                    C, CWc, H, W, logHW, logW, sCorr, sNew);
                gate_v3<<<dim3(gx, S, 1), 256, 0, stream>>>(
                    key, newR, Wg[l] + (size_t)s * wgStep, gzb,
                    C, CWg, H, W, logHW, logW, sNew, sCorr, 0);
                prep_gin<<<dim3(4 * HW / 64, 2 * C / 64), 256, 0, stream>>>(
                    key, newR, gzb, bg[l] + (size_t)s * 2, ginbuf, C, HW);
                prep_w<<<dim3(C * 9, 2 * C / 256), 256, 0, stream>>>(
                    Wd[l] + (size_t)s * C * 2 * C * 9, wtbuf, 2 * C);
                if (l == 0)
                    conv_mfma<128, 0><<<dim3(Mt, C / 128), 256, 0, stream>>>(
                        ginbuf, wtbuf, bd[l] + s * C, totbuf + s * C, 3 * C,
                        nullptr, zp, 2 * C, C, H, W, logHW, logW);
                else
                    conv_mfma<64, 0><<<dim3(Mt, C / 64), 256, 0, stream>>>(
                        ginbuf, wtbuf, bd[l] + s * C, totbuf + s * C, 3 * C,
                        nullptr, zp, 2 * C, C, H, W, logHW, logW);
            }
        }
        prep_w<<<dim3(C * 9, 3 * C / 256), 256, 0, stream>>>(Wc[l], wtbuf, 3 * C);
        if (l == 0)
            conv_mfma<128, 1><<<dim3(Mt, 2), 256, 0, stream>>>(
                totbuf, wtbuf, bc[l], nullptr, 0,
                out + outOff[l], zp, 3 * C, C, H, W, logHW, logW);
        else
            conv_mfma<64, 1><<<dim3(Mt, 8), 256, 0, stream>>>(
                totbuf, wtbuf, bc[l], nullptr, 0,
                out + outOff[l], zp, 3 * C, C, H, W, logHW, logW);
    }
}